// Round 3
// baseline (1424.800 us; speedup 1.0000x reference)
//
#include <hip/hip_runtime.h>

typedef unsigned short u16;

// ---------- bf16 helpers (bf16 buffers handled as u16) ----------
__device__ __forceinline__ float bu2f(u16 u){
  return __uint_as_float(((unsigned int)u) << 16);
}
__device__ __forceinline__ u16 f2bu(float f){
  unsigned int b = __float_as_uint(f);
  unsigned int r = (b + 0x7FFFu + ((b >> 16) & 1u)) >> 16;  // RNE
  return (u16)r;
}
__device__ __forceinline__ void ld4a(float* d, const float* p){
  float4 v = *(const float4*)p;
  d[0]=v.x; d[1]=v.y; d[2]=v.z; d[3]=v.w;
}
__device__ __forceinline__ void st4(float* p, const float* s){
  *(float4*)p = make_float4(s[0], s[1], s[2], s[3]);
}
__device__ __forceinline__ void ld4b(float* d, const u16* p){
  ushort4 v = *(const ushort4*)p;
  d[0]=bu2f(v.x); d[1]=bu2f(v.y); d[2]=bu2f(v.z); d[3]=bu2f(v.w);
}
__device__ __forceinline__ void st4b(u16* p, const float* s){
  ushort4 v;
  v.x=f2bu(s[0]); v.y=f2bu(s[1]); v.z=f2bu(s[2]); v.w=f2bu(s[3]);
  *(ushort4*)p = v;
}

// ---------- workspace layout ----------
// f32 region (float offsets):
#define TABF_RE   0          // exp(-2pi i jk/64)          [64][64]
#define TABF_IM   4096
#define TABIF_RE  8192       // exp(+2pi i jk/64)/64       [64][64]
#define TABIF_IM  12288
#define TABTW_RE  16384      // exp(+2pi i k1*n2/4096)     [k1][n2]
#define TABTW_IM  20480
#define NORMS_OFF 24576      // 2048
#define MMAT_OFF  26624      // 128*16*16*2 = 65536
#define FLAG_OFF  92160      // 1 int (input dtype flag)
#define PRM_OFF   92224      // packed f32 params, 2624 floats
#define WT_OFF    94848      // transposed conv weights, 294912 floats
#define F32_END   389760
// params sub-offsets (within PRM):
#define P_CB   0
#define P_BNS  128
#define P_BNB  256
#define P_TEMP 384
#define P_W1   400
#define P_B1   1424
#define P_S1   1432
#define P_BB1  1440
#define P_W2   1456
#define P_B2   2480
// bf16 region (u16 elements, base = (u16*)(wsf + F32_END)):
#define BPLANE    8388608    // 16*128*4096
// Frb at 0, Fib at BPLANE, A/g (aliased) at 2*BPLANE
// total bytes = 389760*4 + 3*8388608*2 = 51,890,688 (~49.5 MiB)

// ===================== input dtype detection =====================
// If inputs are f32, the EVEN u16 halves (little-endian low mantissa bits) are
// ~uniform random -> ~25% have bf16-exponent >= 0xC0 (|v| >= 2^65).
// If inputs are bf16 (N(0,1)-ish), exponent never reaches 0xC0.
__global__ void k_detect(const u16* __restrict__ xv, int* __restrict__ flag){
  const int t = threadIdx.x;   // 64 threads
  int huge = 0;
  for (int i = 0; i < 16; ++i){
    u16 u = xv[(t*16 + i)*2];
    int e = (u >> 7) & 0xFF;
    huge += (e >= 0xC0) ? 1 : 0;
  }
  #pragma unroll
  for (int off = 32; off > 0; off >>= 1) huge += __shfl_down(huge, off, 64);
  if (t == 0) flag[0] = (huge >= 8) ? 1 : 0;
}

// ===================== tables =====================
__global__ void k_tables(float* ws){
  int idx = blockIdx.x*256 + threadIdx.x;   // 0..4095
  int j = idx >> 6, k = idx & 63;
  int jk = j*k;
  float s, c;
  sincospif(-(float)(jk & 63)/32.0f, &s, &c);
  ws[TABF_RE+idx] = c; ws[TABF_IM+idx] = s;
  sincospif((float)(jk & 63)/32.0f, &s, &c);
  ws[TABIF_RE+idx] = c*(1.f/64.f); ws[TABIF_IM+idx] = s*(1.f/64.f);
  sincospif((float)jk/2048.0f, &s, &c);
  ws[TABTW_RE+idx] = c; ws[TABTW_IM+idx] = s;
}

// ===================== pack small params -> f32 =====================
__global__ void k_pack(const void* cb, const void* bns, const void* bnb, const void* temp,
                       const void* w1, const void* b1, const void* s1, const void* bb1,
                       const void* w2, const void* b2,
                       const int* __restrict__ flg, float* __restrict__ P){
  const int t = threadIdx.x;
  const int f32 = *flg;
  if (f32){
    for (int i = t; i < 128; i += 256){
      P[P_CB+i]  = ((const float*)cb)[i];
      P[P_BNS+i] = ((const float*)bns)[i];
      P[P_BNB+i] = ((const float*)bnb)[i];
      P[P_B2+i]  = ((const float*)b2)[i];
    }
    for (int i = t; i < 1024; i += 256){
      P[P_W1+i] = ((const float*)w1)[i];
      P[P_W2+i] = ((const float*)w2)[i];
    }
    if (t < 8){
      P[P_TEMP+t] = ((const float*)temp)[t];
      P[P_B1+t]   = ((const float*)b1)[t];
      P[P_S1+t]   = ((const float*)s1)[t];
      P[P_BB1+t]  = ((const float*)bb1)[t];
    }
  } else {
    for (int i = t; i < 128; i += 256){
      P[P_CB+i]  = bu2f(((const u16*)cb)[i]);
      P[P_BNS+i] = bu2f(((const u16*)bns)[i]);
      P[P_BNB+i] = bu2f(((const u16*)bnb)[i]);
      P[P_B2+i]  = bu2f(((const u16*)b2)[i]);
    }
    for (int i = t; i < 1024; i += 256){
      P[P_W1+i] = bu2f(((const u16*)w1)[i]);
      P[P_W2+i] = bu2f(((const u16*)w2)[i]);
    }
    if (t < 8){
      P[P_TEMP+t] = bu2f(((const u16*)temp)[t]);
      P[P_B1+t]   = bu2f(((const u16*)b1)[t]);
      P[P_S1+t]   = bu2f(((const u16*)s1)[t]);
      P[P_BB1+t]  = bu2f(((const u16*)bb1)[t]);
    }
  }
}

// transpose conv2_w [d][c*9+t] -> wT [(c*9+t)][d] (f32)
__global__ void k_wprep(const void* __restrict__ w, float* __restrict__ wT,
                        const int* __restrict__ flg){
  const int f32 = *flg;
  int o = blockIdx.x*256 + threadIdx.x;
  if (o < 294912){
    int d = o & 127, c9 = o >> 7;
    int src = d*2304 + c9;
    wT[o] = f32 ? ((const float*)w)[src] : bu2f(((const u16*)w)[src]);
  }
}

// ===================== conv2 (3x3, dilation 3, pad 3) + BN + ReLU =====================
__global__ __launch_bounds__(256) void k_conv(const void* __restrict__ x, const float* __restrict__ wT,
                    const float* __restrict__ prm, const int* __restrict__ flg,
                    u16* __restrict__ A){
  __shared__ float xs[4][10][72];
  const int t  = threadIdx.x;
  const int b  = blockIdx.x >> 5;
  const int r5 = blockIdx.x & 31;
  const int h0 = (r5 >> 1) * 4;
  const int ds = r5 & 1;
  const int wl = t & 63;
  const int wbase = __builtin_amdgcn_readfirstlane(ds*64 + (t >> 6)*16);
  const int f32m = __builtin_amdgcn_readfirstlane(*flg);

  float acc[4][16];
  #pragma unroll
  for (int p = 0; p < 4; ++p)
    #pragma unroll
    for (int dd = 0; dd < 16; ++dd) acc[p][dd] = 0.f;

  for (int ch = 0; ch < 64; ++ch){
    const int c0 = ch*4;
    if (f32m){
      const float* xf = (const float*)x;
      for (int i = t; i < 2800; i += 256){
        int cl = i / 700, rem = i - cl*700;
        int r = rem / 70, col = rem - r*70;
        int hr = h0 + r - 3, xc = col - 3;
        float v = 0.f;
        if (((unsigned)hr < 64u) && ((unsigned)xc < 64u))
          v = xf[(((b*256 + c0 + cl)*64 + hr) << 6) + xc];
        xs[cl][r][col] = v;
      }
    } else {
      const u16* xb = (const u16*)x;
      for (int i = t; i < 2800; i += 256){
        int cl = i / 700, rem = i - cl*700;
        int r = rem / 70, col = rem - r*70;
        int hr = h0 + r - 3, xc = col - 3;
        float v = 0.f;
        if (((unsigned)hr < 64u) && ((unsigned)xc < 64u))
          v = bu2f(xb[(((b*256 + c0 + cl)*64 + hr) << 6) + xc]);
        xs[cl][r][col] = v;
      }
    }
    __syncthreads();
    #pragma unroll
    for (int cl = 0; cl < 4; ++cl){
      float xv[4][9];
      #pragma unroll
      for (int ky = 0; ky < 3; ++ky)
        #pragma unroll
        for (int kx = 0; kx < 3; ++kx)
          #pragma unroll
          for (int p = 0; p < 4; ++p)
            xv[p][ky*3+kx] = xs[cl][p + 3*ky][wl + 3*kx];
      #pragma unroll
      for (int tap = 0; tap < 9; ++tap){
        const float* wrow = wT + ((c0+cl)*9 + tap)*128 + wbase;
        float wv[16];
        ld4a(wv, wrow); ld4a(wv+4, wrow+4); ld4a(wv+8, wrow+8); ld4a(wv+12, wrow+12);
        #pragma unroll
        for (int p = 0; p < 4; ++p){
          const float a = xv[p][tap];
          #pragma unroll
          for (int dd = 0; dd < 16; ++dd)
            acc[p][dd] = fmaf(a, wv[dd], acc[p][dd]);
        }
      }
    }
    __syncthreads();
  }
  #pragma unroll
  for (int dd = 0; dd < 16; ++dd){
    const int d = wbase + dd;
    const float sc = prm[P_BNS + d];
    const float bi = prm[P_CB + d]*sc + prm[P_BNB + d];
    #pragma unroll
    for (int p = 0; p < 4; ++p){
      float v = fmaxf(fmaf(acc[p][dd], sc, bi), 0.f);
      A[(((b*128 + d)*64 + (h0+p)) << 6) + wl] = f2bu(v);
    }
  }
}

// ===================== fft2 (64x64, forward) per (b,c) image =====================
__global__ __launch_bounds__(256) void k_fft2(const u16* __restrict__ A, u16* __restrict__ Frb,
                                              u16* __restrict__ Fib, const float* __restrict__ ws){
  __shared__ float Tre[64][68], Tim[64][68];
  const int bc = blockIdx.x, t = threadIdx.x;
  const int lo = t & 15, hi = t >> 4;
  const float* tfr = ws + TABF_RE;
  const float* tfi = ws + TABF_IM;
  const u16* img = A + bc*4096;
  {
    const int k0 = lo*4, h0 = hi*4;
    float ar[4][4] = {}, ai[4][4] = {};
    for (int w4 = 0; w4 < 64; w4 += 4){
      float av[4][4];
      #pragma unroll
      for (int i = 0; i < 4; ++i) ld4b(av[i], img + (h0+i)*64 + w4);
      #pragma unroll
      for (int u = 0; u < 4; ++u){
        float er[4], ei[4];
        ld4a(er, tfr + (w4+u)*64 + k0);
        ld4a(ei, tfi + (w4+u)*64 + k0);
        #pragma unroll
        for (int i = 0; i < 4; ++i){
          const float a = av[i][u];
          #pragma unroll
          for (int j = 0; j < 4; ++j){
            ar[i][j] = fmaf(a, er[j], ar[i][j]);
            ai[i][j] = fmaf(a, ei[j], ai[i][j]);
          }
        }
      }
    }
    #pragma unroll
    for (int i = 0; i < 4; ++i){ st4(&Tre[h0+i][k0], ar[i]); st4(&Tim[h0+i][k0], ai[i]); }
  }
  __syncthreads();
  {
    const int k2o = lo*4, k1o = hi*4;
    float br[4][4] = {}, bi[4][4] = {};
    for (int h = 0; h < 64; ++h){
      float er[4], ei[4], cr[4], ci[4];
      ld4a(er, tfr + h*64 + k1o);
      ld4a(ei, tfi + h*64 + k1o);
      ld4a(cr, &Tre[h][k2o]);
      ld4a(ci, &Tim[h][k2o]);
      #pragma unroll
      for (int i = 0; i < 4; ++i)
        #pragma unroll
        for (int j = 0; j < 4; ++j){
          br[i][j] += er[i]*cr[j] - ei[i]*ci[j];
          bi[i][j] += er[i]*ci[j] + ei[i]*cr[j];
        }
    }
    #pragma unroll
    for (int i = 0; i < 4; ++i){
      st4b(Frb + bc*4096 + (k1o+i)*64 + k2o, br[i]);
      st4b(Fib + bc*4096 + (k1o+i)*64 + k2o, bi[i]);
    }
  }
}

// ===================== row norms =====================
__global__ __launch_bounds__(256) void k_norms(const u16* __restrict__ Frb, const u16* __restrict__ Fib,
                                               float* __restrict__ norms){
  const int bc = blockIdx.x, t = threadIdx.x;
  const u16* pr = Frb + bc*4096;
  const u16* pi = Fib + bc*4096;
  float s = 0.f;
  for (int i = t*4; i < 4096; i += 1024){
    float a[4], b[4];
    ld4b(a, pr + i); ld4b(b, pi + i);
    #pragma unroll
    for (int k = 0; k < 4; ++k) s = fmaf(a[k],a[k],fmaf(b[k],b[k],s));
  }
  #pragma unroll
  for (int off = 32; off > 0; off >>= 1) s += __shfl_down(s, off, 64);
  __shared__ float red[4];
  if ((t & 63) == 0) red[t >> 6] = s;
  __syncthreads();
  if (t == 0){
    float tot = red[0]+red[1]+red[2]+red[3];
    norms[bc] = fmaxf(sqrtf(tot), 1e-12f);
  }
}

// ===================== attention: Gram + dual softmax + fold c-axis ifft =====================
__global__ __launch_bounds__(256) void k_attn(const u16* __restrict__ Frb, const u16* __restrict__ Fib,
                                              const float* __restrict__ norms, const float* __restrict__ prm,
                                              float* __restrict__ wsM){
  __shared__ float SR[16][260];
  __shared__ float SI[16][260];
  __shared__ float AR[16][17], AI[16][17];
  const int bh = blockIdx.x;
  const int b = bh >> 3, h = bh & 7;
  const int t = threadIdx.x;
  const int tile = t & 15, part = t >> 4;
  const int i0 = (tile >> 2)*4, j0 = (tile & 3)*4;
  const u16* fr = Frb + (b*128 + h*16)*4096;
  const u16* fi = Fib + (b*128 + h*16)*4096;
  float gr[4][4] = {}, gi[4][4] = {};
  for (int nc = 0; nc < 16; ++nc){
    const int nb = nc*256;
    for (int idx = t; idx < 1024; idx += 256){
      int r = idx >> 6, col = (idx & 63)*4;
      float tmp[4];
      ld4b(tmp, fr + r*4096 + nb + col); st4(&SR[r][col], tmp);
      ld4b(tmp, fi + r*4096 + nb + col); st4(&SI[r][col], tmp);
    }
    __syncthreads();
    #pragma unroll
    for (int s = 0; s < 4; ++s){
      const int nn = part*16 + s*4;
      float arr[4][4], ari[4][4], brr[4][4], bri[4][4];
      #pragma unroll
      for (int i = 0; i < 4; ++i){
        ld4a(arr[i], &SR[i0+i][nn]);
        ld4a(ari[i], &SI[i0+i][nn]);
        ld4a(brr[i], &SR[j0+i][nn]);
        ld4a(bri[i], &SI[j0+i][nn]);
      }
      #pragma unroll
      for (int i = 0; i < 4; ++i)
        #pragma unroll
        for (int j = 0; j < 4; ++j)
          #pragma unroll
          for (int m = 0; m < 4; ++m){
            gr[i][j] += arr[i][m]*brr[j][m] - ari[i][m]*bri[j][m];
            gi[i][j] += arr[i][m]*bri[j][m] + ari[i][m]*brr[j][m];
          }
    }
    __syncthreads();
  }
  float* redR = &SR[0][0];
  float* redI = &SI[0][0];
  #pragma unroll
  for (int e = 0; e < 16; ++e){
    redR[t*16 + e] = gr[e>>2][e&3];
    redI[t*16 + e] = gi[e>>2][e&3];
  }
  __syncthreads();
  {
    const int tile2 = t >> 4, e2 = t & 15;
    float sr = 0.f, si = 0.f;
    for (int p = 0; p < 16; ++p){
      sr += redR[(p*16 + tile2)*16 + e2];
      si += redI[(p*16 + tile2)*16 + e2];
    }
    const int ii = (tile2 >> 2)*4 + (e2 >> 2);
    const int jj = (tile2 & 3)*4 + (e2 & 3);
    const float tm = prm[P_TEMP + h];
    const float sc = tm / (norms[b*128 + h*16 + ii] * norms[b*128 + h*16 + jj]);
    AR[ii][jj] = sr*sc;
    AI[ii][jj] = si*sc;
  }
  __syncthreads();
  if (t < 32){
    float* row = (t < 16) ? AR[t & 15] : AI[t & 15];
    float mx = row[0];
    for (int j2 = 1; j2 < 16; ++j2) mx = fmaxf(mx, row[j2]);
    float s = 0.f, e[16];
    for (int j2 = 0; j2 < 16; ++j2){ e[j2] = expf(row[j2] - mx); s += e[j2]; }
    float inv = 1.f/s;
    for (int j2 = 0; j2 < 16; ++j2) row[j2] = e[j2]*inv;
  }
  __syncthreads();
  {
    const int mi = t >> 4, mj = t & 15;
    float mr = 0.f, mim = 0.f;
    #pragma unroll
    for (int p = 0; p < 16; ++p){
      float sv, cv;
      sincospif((float)((mi*p) & 15)/8.0f, &sv, &cv);
      const float arv = AR[p][mj], aiv = AI[p][mj];
      mr  += cv*arv - sv*aiv;
      mim += cv*aiv + sv*arv;
    }
    wsM[bh*512 + t*2]     = mr*(1.f/16.f);
    wsM[bh*512 + t*2 + 1] = mim*(1.f/16.f);
  }
}

// ===================== gating MLP -> g plane (bf16) =====================
__global__ __launch_bounds__(256) void k_gate(const u16* __restrict__ Frb,
                                              const float* __restrict__ prm,
                                              u16* __restrict__ g){
  __shared__ float W1T[128][8];
  __shared__ float W2[128][8];
  __shared__ float B1v[8], S1v[8], BB1v[8];
  __shared__ float B2v[128];
  const int t = threadIdx.x;
  for (int i = t; i < 1024; i += 256){
    W1T[i & 127][i >> 7] = prm[P_W1 + i];   // w1 flat [k][c]
    W2[i >> 3][i & 7]    = prm[P_W2 + i];   // w2 flat [c][k]
  }
  if (t < 8){ B1v[t] = prm[P_B1+t]; S1v[t] = prm[P_S1+t]; BB1v[t] = prm[P_BB1+t]; }
  if (t < 128) B2v[t] = prm[P_B2+t];
  __syncthreads();
  const int pix = blockIdx.x*256 + t;
  const int b = pix >> 12, n = pix & 4095;
  const u16* fr = Frb + b*128*4096 + n;
  float q[8] = {};
  for (int c = 0; c < 128; ++c){
    const float v = bu2f(fr[c*4096]);
    float wa[4], wb[4];
    ld4a(wa, &W1T[c][0]); ld4a(wb, &W1T[c][4]);
    #pragma unroll
    for (int k = 0; k < 4; ++k){ q[k] = fmaf(wa[k], v, q[k]); q[4+k] = fmaf(wb[k], v, q[4+k]); }
  }
  float qa[8];
  #pragma unroll
  for (int k = 0; k < 8; ++k)
    qa[k] = fmaxf(fmaf(q[k] + B1v[k], S1v[k], BB1v[k]), 0.f);
  u16* grow = g + b*128*4096 + n;
  for (int c = 0; c < 128; ++c){
    float wa[4], wb[4];
    ld4a(wa, &W2[c][0]); ld4a(wb, &W2[c][4]);
    float acc = B2v[c];
    #pragma unroll
    for (int k = 0; k < 4; ++k) acc += wa[k]*qa[k] + wb[k]*qa[4+k];
    grow[c*4096] = f2bu(1.f/(1.f + expf(-acc)));
  }
}

// ===================== out_l = |ifft2(g*F)| + x  (channels 128..255), f32 out =====================
// MUST run before k_ifft4096 (F destroyed in place there)
__global__ __launch_bounds__(256) void k_outl(const u16* __restrict__ Frb, const u16* __restrict__ Fib,
                                              const u16* __restrict__ g, const void* __restrict__ x,
                                              float* __restrict__ out, const float* __restrict__ ws,
                                              const int* __restrict__ flg){
  __shared__ float Tre[64][68], Tim[64][68];
  const int bc = blockIdx.x, t = threadIdx.x;
  const int b = bc >> 7, c = bc & 127;
  const int lo = t & 15, hi = t >> 4;
  const int f32m = __builtin_amdgcn_readfirstlane(*flg);
  const float* tir = ws + TABIF_RE;
  const float* tii = ws + TABIF_IM;
  const u16* pg = g   + bc*4096;
  const u16* pr = Frb + bc*4096;
  const u16* pi = Fib + bc*4096;
  {
    const int k0 = lo*4, h0 = hi*4;
    float ar[4][4] = {}, ai[4][4] = {};
    for (int w4 = 0; w4 < 64; w4 += 4){
      float gv[4][4], fre[4][4], fim[4][4];
      #pragma unroll
      for (int i = 0; i < 4; ++i){
        ld4b(gv[i],  pg + (h0+i)*64 + w4);
        ld4b(fre[i], pr + (h0+i)*64 + w4);
        ld4b(fim[i], pi + (h0+i)*64 + w4);
      }
      #pragma unroll
      for (int u = 0; u < 4; ++u){
        float er[4], ei[4];
        ld4a(er, tir + (w4+u)*64 + k0);
        ld4a(ei, tii + (w4+u)*64 + k0);
        #pragma unroll
        for (int i = 0; i < 4; ++i){
          const float prv = gv[i][u]*fre[i][u];
          const float piv = gv[i][u]*fim[i][u];
          #pragma unroll
          for (int j = 0; j < 4; ++j){
            ar[i][j] += prv*er[j] - piv*ei[j];
            ai[i][j] += prv*ei[j] + piv*er[j];
          }
        }
      }
    }
    #pragma unroll
    for (int i = 0; i < 4; ++i){ st4(&Tre[h0+i][k0], ar[i]); st4(&Tim[h0+i][k0], ai[i]); }
  }
  __syncthreads();
  {
    const int k2o = lo*4, k1o = hi*4;
    float yr[4][4] = {}, yi[4][4] = {};
    for (int h = 0; h < 64; ++h){
      float er[4], ei[4], cr[4], ci[4];
      ld4a(er, tir + h*64 + k1o);
      ld4a(ei, tii + h*64 + k1o);
      ld4a(cr, &Tre[h][k2o]);
      ld4a(ci, &Tim[h][k2o]);
      #pragma unroll
      for (int i = 0; i < 4; ++i)
        #pragma unroll
        for (int j = 0; j < 4; ++j){
          yr[i][j] += er[i]*cr[j] - ei[i]*ci[j];
          yi[i][j] += er[i]*ci[j] + ei[i]*cr[j];
        }
    }
    const int base = (b*256 + 128 + c)*4096;
    #pragma unroll
    for (int i = 0; i < 4; ++i){
      const int o = base + (k1o+i)*64 + k2o;
      float xr[4];
      if (f32m) ld4a(xr, (const float*)x + o); else ld4b(xr, (const u16*)x + o);
      float ov[4];
      #pragma unroll
      for (int j = 0; j < 4; ++j)
        ov[j] = sqrtf(yr[i][j]*yr[i][j] + yi[i][j]*yi[i][j]) + xr[j];
      st4(out + o, ov);
    }
  }
}

// ===================== 4096-pt IFFT per (b,c) row, four-step, in place =====================
__global__ __launch_bounds__(256) void k_ifft4096(u16* __restrict__ Frb, u16* __restrict__ Fib,
                                                  const float* __restrict__ ws){
  __shared__ float Cre[64][68], Cim[64][68];   // transposed: [n2][k1]
  const int bc = blockIdx.x, t = threadIdx.x;
  const int lo = t & 15, hi = t >> 4;
  const float* tir = ws + TABIF_RE;
  const float* tii = ws + TABIF_IM;
  const float* twr = ws + TABTW_RE;
  const float* twi = ws + TABTW_IM;
  u16* fr = Frb + bc*4096;
  u16* fi = Fib + bc*4096;
  {
    const int k10 = lo*4, n20 = hi*4;
    float ar[4][4] = {}, ai[4][4] = {};
    for (int n1 = 0; n1 < 64; ++n1){
      float er[4], ei[4], xr[4], xi[4];
      ld4a(er, tir + n1*64 + k10);
      ld4a(ei, tii + n1*64 + k10);
      ld4b(xr, fr + n1*64 + n20);
      ld4b(xi, fi + n1*64 + n20);
      #pragma unroll
      for (int i = 0; i < 4; ++i)
        #pragma unroll
        for (int j = 0; j < 4; ++j){
          ar[i][j] += er[i]*xr[j] - ei[i]*xi[j];
          ai[i][j] += er[i]*xi[j] + ei[i]*xr[j];
        }
    }
    float crT[4][4], ciT[4][4];
    #pragma unroll
    for (int i = 0; i < 4; ++i){
      float wr[4], wi[4];
      ld4a(wr, twr + (k10+i)*64 + n20);
      ld4a(wi, twi + (k10+i)*64 + n20);
      #pragma unroll
      for (int j = 0; j < 4; ++j){
        crT[j][i] = ar[i][j]*wr[j] - ai[i][j]*wi[j];
        ciT[j][i] = ar[i][j]*wi[j] + ai[i][j]*wr[j];
      }
    }
    #pragma unroll
    for (int j = 0; j < 4; ++j){
      st4(&Cre[n20+j][k10], crT[j]);
      st4(&Cim[n20+j][k10], ciT[j]);
    }
  }
  __syncthreads();
  {
    const int k1o = lo*4, k2o = hi*4;
    float dr[4][4] = {}, di[4][4] = {};
    for (int n2 = 0; n2 < 64; ++n2){
      float er[4], ei[4], cr[4], ci[4];
      ld4a(er, tir + n2*64 + k2o);
      ld4a(ei, tii + n2*64 + k2o);
      ld4a(cr, &Cre[n2][k1o]);
      ld4a(ci, &Cim[n2][k1o]);
      #pragma unroll
      for (int i = 0; i < 4; ++i)
        #pragma unroll
        for (int j = 0; j < 4; ++j){
          dr[i][j] += cr[i]*er[j] - ci[i]*ei[j];
          di[i][j] += cr[i]*ei[j] + ci[i]*er[j];
        }
    }
    #pragma unroll
    for (int j = 0; j < 4; ++j){
      float o_r[4], o_i[4];
      #pragma unroll
      for (int i = 0; i < 4; ++i){ o_r[i] = dr[i][j]; o_i[i] = di[i][j]; }
      st4b(fr + (k2o+j)*64 + k1o, o_r);
      st4b(fi + (k2o+j)*64 + k1o, o_i);
    }
  }
}

// ===================== out_f = |M @ Z| + x  (channels 0..127), f32 out =====================
__global__ __launch_bounds__(256) void k_outf(const u16* __restrict__ Zr, const u16* __restrict__ Zi,
                                              const float* __restrict__ wsM, const void* __restrict__ x,
                                              float* __restrict__ out, const int* __restrict__ flg){
  __shared__ float MreT[16][20], MimT[16][20];   // [j][i]
  const int gb = blockIdx.x;           // 0..2047
  const int bh = gb & 127, nch = gb >> 7;
  const int b = bh >> 3, h = bh & 7;
  const int t = threadIdx.x;
  const int f32m = __builtin_amdgcn_readfirstlane(*flg);
  {
    const int i = t >> 4, j = t & 15;
    MreT[j][i] = wsM[bh*512 + t*2];
    MimT[j][i] = wsM[bh*512 + t*2 + 1];
  }
  __syncthreads();
  const int i0 = (t & 3)*4;
  const int nn = nch*256 + (t >> 2)*4;
  const u16* zr = Zr + (b*128 + h*16)*4096 + nn;
  const u16* zi = Zi + (b*128 + h*16)*4096 + nn;
  float accr[4][4] = {}, acci[4][4] = {};
  #pragma unroll
  for (int j = 0; j < 16; ++j){
    float mr[4], mi[4], vr[4], vi[4];
    ld4a(mr, &MreT[j][i0]);
    ld4a(mi, &MimT[j][i0]);
    ld4b(vr, zr + j*4096);
    ld4b(vi, zi + j*4096);
    #pragma unroll
    for (int i = 0; i < 4; ++i)
      #pragma unroll
      for (int n = 0; n < 4; ++n){
        accr[i][n] += mr[i]*vr[n] - mi[i]*vi[n];
        acci[i][n] += mr[i]*vi[n] + mi[i]*vr[n];
      }
  }
  #pragma unroll
  for (int i = 0; i < 4; ++i){
    const int o = (b*256 + h*16 + i0 + i)*4096 + nn;
    float xr[4];
    if (f32m) ld4a(xr, (const float*)x + o); else ld4b(xr, (const u16*)x + o);
    float ov[4];
    #pragma unroll
    for (int n = 0; n < 4; ++n)
      ov[n] = sqrtf(accr[i][n]*accr[i][n] + acci[i][n]*acci[i][n]) + xr[n];
    st4(out + o, ov);
  }
}

// ===================== launch =====================
extern "C" void kernel_launch(void* const* d_in, const int* in_sizes, int n_in,
                              void* d_out, int out_size, void* d_ws, size_t ws_size,
                              hipStream_t stream) {
  const void* x        = d_in[0];
  const void* conv2_w  = d_in[1];
  const void* conv2_b  = d_in[2];
  const void* bn2_s    = d_in[3];
  const void* bn2_b    = d_in[4];
  const void* temp     = d_in[5];
  const void* w1_w     = d_in[6];
  const void* w1_b     = d_in[7];
  const void* bnw_s    = d_in[8];
  const void* bnw_b    = d_in[9];
  const void* w2_w     = d_in[10];
  const void* w2_b     = d_in[11];
  float* out = (float*)d_out;
  float* wsf = (float*)d_ws;

  // guard: if ws too small, no-op -> absmax 6.59 (distinguishable diagnostic)
  if (ws_size < (size_t)(F32_END*4) + 3u*(size_t)BPLANE*2u) return;

  int* flag = (int*)(wsf + FLAG_OFF);
  float* prm = wsf + PRM_OFF;
  u16* wsb = (u16*)(wsf + F32_END);
  u16* Frb = wsb;
  u16* Fib = wsb + BPLANE;
  u16* Ab  = wsb + 2*BPLANE;   // conv output; later aliased by g (A dead after k_fft2)
  u16* g   = Ab;

  k_detect<<<1, 64, 0, stream>>>((const u16*)x, flag);
  k_tables<<<16, 256, 0, stream>>>(wsf);
  k_pack<<<1, 256, 0, stream>>>(conv2_b, bn2_s, bn2_b, temp, w1_w, w1_b, bnw_s, bnw_b,
                                w2_w, w2_b, flag, prm);
  k_wprep<<<1152, 256, 0, stream>>>(conv2_w, wsf + WT_OFF, flag);
  k_conv<<<512, 256, 0, stream>>>(x, wsf + WT_OFF, prm, flag, Ab);
  k_fft2<<<2048, 256, 0, stream>>>(Ab, Frb, Fib, wsf);
  k_norms<<<2048, 256, 0, stream>>>(Frb, Fib, wsf + NORMS_OFF);
  k_attn<<<128, 256, 0, stream>>>(Frb, Fib, wsf + NORMS_OFF, prm, wsf + MMAT_OFF);
  k_gate<<<256, 256, 0, stream>>>(Frb, prm, g);
  k_outl<<<2048, 256, 0, stream>>>(Frb, Fib, g, x, out, wsf, flag);
  k_ifft4096<<<2048, 256, 0, stream>>>(Frb, Fib, wsf);          // F -> Z in place
  k_outf<<<2048, 256, 0, stream>>>(Frb, Fib, wsf + MMAT_OFF, x, out, flag);
}

// Round 4
// 788.807 us; speedup vs baseline: 1.8063x; 1.8063x over previous
//
#include <hip/hip_runtime.h>

typedef unsigned short u16;
typedef short short8 __attribute__((ext_vector_type(8)));
typedef float f32x4 __attribute__((ext_vector_type(4)));

// ---------- bf16 helpers ----------
__device__ __forceinline__ float bu2f(u16 u){
  return __uint_as_float(((unsigned int)u) << 16);
}
__device__ __forceinline__ u16 f2bu(float f){
  unsigned int b = __float_as_uint(f);
  unsigned int r = (b + 0x7FFFu + ((b >> 16) & 1u)) >> 16;  // RNE
  return (u16)r;
}
__device__ __forceinline__ void ld4a(float* d, const float* p){
  float4 v = *(const float4*)p;
  d[0]=v.x; d[1]=v.y; d[2]=v.z; d[3]=v.w;
}
__device__ __forceinline__ void st4(float* p, const float* s){
  *(float4*)p = make_float4(s[0], s[1], s[2], s[3]);
}
__device__ __forceinline__ void ld4b(float* d, const u16* p){
  ushort4 v = *(const ushort4*)p;
  d[0]=bu2f(v.x); d[1]=bu2f(v.y); d[2]=bu2f(v.z); d[3]=bu2f(v.w);
}
__device__ __forceinline__ void st4b(u16* p, const float* s){
  ushort4 v;
  v.x=f2bu(s[0]); v.y=f2bu(s[1]); v.z=f2bu(s[2]); v.w=f2bu(s[3]);
  *(ushort4*)p = v;
}

// ---------- workspace layout ----------
#define TABF_RE   0
#define TABF_IM   4096
#define TABIF_RE  8192
#define TABIF_IM  12288
#define TABTW_RE  16384
#define TABTW_IM  20480
#define NORMS_OFF 24576
#define MMAT_OFF  26624
#define FLAG_OFF  92160
#define PRM_OFF   92224
#define WT_OFF    94848      // wT2 bf16 weights (294912 u16 = 0.59MB), 16B-aligned
#define F32_END   389760
// params sub-offsets:
#define P_CB   0
#define P_BNS  128
#define P_BNB  256
#define P_TEMP 384
#define P_W1   400
#define P_B1   1424
#define P_S1   1432
#define P_BB1  1440
#define P_W2   1456
#define P_B2   2480
// bf16 region:
#define BPLANE    8388608
// x_t (channel-last transposed x, 16*64*64*256 u16 = 2*BPLANE) aliases Frb+Fib
// (x_t dead after k_cmm; Frb/Fib written by k_fft2 afterwards)
// A/g plane at 2*BPLANE. total = 389760*4 + 3*BPLANE*2 = 51,890,688 B

// ===================== input dtype detection =====================
__global__ void k_detect(const u16* __restrict__ xv, int* __restrict__ flag){
  const int t = threadIdx.x;
  int huge = 0;
  for (int i = 0; i < 16; ++i){
    u16 u = xv[(t*16 + i)*2];
    int e = (u >> 7) & 0xFF;
    huge += (e >= 0xC0) ? 1 : 0;
  }
  #pragma unroll
  for (int off = 32; off > 0; off >>= 1) huge += __shfl_down(huge, off, 64);
  if (t == 0) flag[0] = (huge >= 8) ? 1 : 0;
}

// ===================== tables =====================
__global__ void k_tables(float* ws){
  int idx = blockIdx.x*256 + threadIdx.x;
  int j = idx >> 6, k = idx & 63;
  int jk = j*k;
  float s, c;
  sincospif(-(float)(jk & 63)/32.0f, &s, &c);
  ws[TABF_RE+idx] = c; ws[TABF_IM+idx] = s;
  sincospif((float)(jk & 63)/32.0f, &s, &c);
  ws[TABIF_RE+idx] = c*(1.f/64.f); ws[TABIF_IM+idx] = s*(1.f/64.f);
  sincospif((float)jk/2048.0f, &s, &c);
  ws[TABTW_RE+idx] = c; ws[TABTW_IM+idx] = s;
}

// ===================== pack small params -> f32 =====================
__global__ void k_pack(const void* cb, const void* bns, const void* bnb, const void* temp,
                       const void* w1, const void* b1, const void* s1, const void* bb1,
                       const void* w2, const void* b2,
                       const int* __restrict__ flg, float* __restrict__ P){
  const int t = threadIdx.x;
  const int f32 = *flg;
  if (f32){
    for (int i = t; i < 128; i += 256){
      P[P_CB+i]  = ((const float*)cb)[i];
      P[P_BNS+i] = ((const float*)bns)[i];
      P[P_BNB+i] = ((const float*)bnb)[i];
      P[P_B2+i]  = ((const float*)b2)[i];
    }
    for (int i = t; i < 1024; i += 256){
      P[P_W1+i] = ((const float*)w1)[i];
      P[P_W2+i] = ((const float*)w2)[i];
    }
    if (t < 8){
      P[P_TEMP+t] = ((const float*)temp)[t];
      P[P_B1+t]   = ((const float*)b1)[t];
      P[P_S1+t]   = ((const float*)s1)[t];
      P[P_BB1+t]  = ((const float*)bb1)[t];
    }
  } else {
    for (int i = t; i < 128; i += 256){
      P[P_CB+i]  = bu2f(((const u16*)cb)[i]);
      P[P_BNS+i] = bu2f(((const u16*)bns)[i]);
      P[P_BNB+i] = bu2f(((const u16*)bnb)[i]);
      P[P_B2+i]  = bu2f(((const u16*)b2)[i]);
    }
    for (int i = t; i < 1024; i += 256){
      P[P_W1+i] = bu2f(((const u16*)w1)[i]);
      P[P_W2+i] = bu2f(((const u16*)w2)[i]);
    }
    if (t < 8){
      P[P_TEMP+t] = bu2f(((const u16*)temp)[t]);
      P[P_B1+t]   = bu2f(((const u16*)b1)[t]);
      P[P_S1+t]   = bu2f(((const u16*)s1)[t]);
      P[P_BB1+t]  = bu2f(((const u16*)bb1)[t]);
    }
  }
}

// ===================== weight prep for MFMA conv =====================
// wT2 linear u16 index: (((tap*8 + chunk)*512 + o*128 + n)*8 + j)
// value = conv_w[d=n][c = chunk*32 + o*8 + j][tap] * bn_scale[n]   (bf16)
__global__ void k_wprep2(const void* __restrict__ w, u16* __restrict__ wT2,
                         const float* __restrict__ prm, const int* __restrict__ flg){
  const int f32 = *flg;
  int U = blockIdx.x*256 + threadIdx.x;
  if (U < 294912){
    int j = U & 7;
    int E = U >> 3;
    int n = E & 127;
    int o = (E >> 7) & 3;
    int tc = E >> 9;
    int chunk = tc & 7, tap = tc >> 3;
    int c = chunk*32 + o*8 + j;
    int src = n*2304 + c*9 + tap;
    float v = f32 ? ((const float*)w)[src] : bu2f(((const u16*)w)[src]);
    wT2[U] = f2bu(v * prm[P_BNS + n]);
  }
}

// ===================== x transpose: NCHW f32/bf16 -> [b][h][w][c] bf16 =====================
__global__ __launch_bounds__(256) void k_trans(const void* __restrict__ x, u16* __restrict__ xt,
                                               const int* __restrict__ flg){
  __shared__ u16 L[256*66];
  const int t = threadIdx.x;
  const int b = blockIdx.x >> 6, h = blockIdx.x & 63;
  const int f32m = __builtin_amdgcn_readfirstlane(*flg);
  if (f32m){
    const float* xf = (const float*)x;
    for (int i = t; i < 16384; i += 256){
      int c = i >> 6, w = i & 63;
      L[c*66 + w] = f2bu(xf[((b*256 + c)*64 + h)*64 + w]);
    }
  } else {
    const u16* xb = (const u16*)x;
    for (int i = t; i < 16384; i += 256){
      int c = i >> 6, w = i & 63;
      L[c*66 + w] = xb[((b*256 + c)*64 + h)*64 + w];
    }
  }
  __syncthreads();
  u16* dst = xt + ((b*64 + h)*64)*256;
  for (int j = t; j < 16384; j += 256){
    int w = j >> 8, c = j & 255;
    dst[w*256 + c] = L[c*66 + w];
  }
}

// ===================== MFMA implicit-GEMM conv (3x3 dil=3 pad=3) + BN + ReLU =====================
// grid 256 = b(16) x mtile(16); block 256 (4 waves). M=256 pixels, N=128 ch, K=2304.
// A-frags: direct global->reg from channel-last x_t (per-lane bounds = padding).
// B: one tap (64KB) staged in LDS, 8 barrier-free K-chunks inside.
__global__ __launch_bounds__(256) void k_cmm(const u16* __restrict__ xt, const u16* __restrict__ wT2,
                                             const float* __restrict__ prm, u16* __restrict__ A){
  __shared__ uint4 sm4[4096];    // 64KB: B for one tap; epilogue reuses as f32 C[16][261]
  const int t = threadIdx.x;
  const int bb = blockIdx.x >> 4;
  const int mtile = blockIdx.x & 15;
  const int h0 = mtile*4;
  const int lane = t & 63, wave = t >> 6;
  const int quad = lane >> 4, lr = lane & 15;

  f32x4 acc[4][8];
  #pragma unroll
  for (int mi = 0; mi < 4; ++mi)
    #pragma unroll
    for (int nt = 0; nt < 8; ++nt)
      acc[mi][nt] = (f32x4){0.f,0.f,0.f,0.f};

  const u16* smB = (const u16*)sm4;
  const short8 zz = {0,0,0,0,0,0,0,0};

  for (int tap = 0; tap < 9; ++tap){
    const int ky = tap/3, kx = tap - ky*3;
    // stage B for this tap
    __syncthreads();
    {
      const uint4* src = (const uint4*)(wT2 + tap*32768);
      #pragma unroll
      for (int i = 0; i < 16; ++i) sm4[t + 256*i] = src[t + 256*i];
    }
    __syncthreads();

    const int hg = h0 + wave + 3*ky - 3;                  // uniform per wave
    const bool hok = ((unsigned)hg < 64u);
    const u16* abase = xt + ((bb*64 + hg)*64)*256 + quad*8;

    for (int chunk = 0; chunk < 8; ++chunk){
      // A fragments (global -> reg)
      short8 av[4];
      #pragma unroll
      for (int mi = 0; mi < 4; ++mi){
        const int wg = mi*16 + lr + 3*kx - 3;
        short8 v = zz;
        if (hok && ((unsigned)wg < 64u))
          v = *(const short8*)(abase + wg*256 + chunk*32);
        av[mi] = v;
      }
      // B fragments (LDS)
      short8 bv[8];
      #pragma unroll
      for (int nt = 0; nt < 8; ++nt)
        bv[nt] = *(const short8*)(smB + (chunk*512 + quad*128 + nt*16 + lr)*8);
      // MFMA
      #pragma unroll
      for (int mi = 0; mi < 4; ++mi)
        #pragma unroll
        for (int nt = 0; nt < 8; ++nt)
          acc[mi][nt] = __builtin_amdgcn_mfma_f32_16x16x32_bf16(av[mi], bv[nt], acc[mi][nt], 0, 0, 0);
    }
  }

  // epilogue: transpose via LDS, +bias, ReLU, bf16 NCHW store
  float* C = (float*)sm4;   // [16][261]
  u16* outb = A + (bb*128)*4096 + mtile*256;
  __syncthreads();
  for (int nt = 0; nt < 8; ++nt){
    #pragma unroll
    for (int mi = 0; mi < 4; ++mi)
      #pragma unroll
      for (int r = 0; r < 4; ++r){
        int m = wave*64 + mi*16 + quad*4 + r;
        C[lr*261 + m] = acc[mi][nt][r];
      }
    __syncthreads();
    #pragma unroll
    for (int dd = 0; dd < 16; ++dd){
      int d = nt*16 + dd;
      float bi = prm[P_CB + d]*prm[P_BNS + d] + prm[P_BNB + d];
      float v = fmaxf(C[dd*261 + t] + bi, 0.f);
      outb[d*4096 + t] = f2bu(v);
    }
    __syncthreads();
  }
}

// ===================== fft2 (64x64, forward) per (b,c) image =====================
__global__ __launch_bounds__(256) void k_fft2(const u16* __restrict__ A, u16* __restrict__ Frb,
                                              u16* __restrict__ Fib, const float* __restrict__ ws){
  __shared__ float Tre[64][68], Tim[64][68];
  const int bc = blockIdx.x, t = threadIdx.x;
  const int lo = t & 15, hi = t >> 4;
  const float* tfr = ws + TABF_RE;
  const float* tfi = ws + TABF_IM;
  const u16* img = A + bc*4096;
  {
    const int k0 = lo*4, h0 = hi*4;
    float ar[4][4] = {}, ai[4][4] = {};
    for (int w4 = 0; w4 < 64; w4 += 4){
      float av[4][4];
      #pragma unroll
      for (int i = 0; i < 4; ++i) ld4b(av[i], img + (h0+i)*64 + w4);
      #pragma unroll
      for (int u = 0; u < 4; ++u){
        float er[4], ei[4];
        ld4a(er, tfr + (w4+u)*64 + k0);
        ld4a(ei, tfi + (w4+u)*64 + k0);
        #pragma unroll
        for (int i = 0; i < 4; ++i){
          const float a = av[i][u];
          #pragma unroll
          for (int j = 0; j < 4; ++j){
            ar[i][j] = fmaf(a, er[j], ar[i][j]);
            ai[i][j] = fmaf(a, ei[j], ai[i][j]);
          }
        }
      }
    }
    #pragma unroll
    for (int i = 0; i < 4; ++i){ st4(&Tre[h0+i][k0], ar[i]); st4(&Tim[h0+i][k0], ai[i]); }
  }
  __syncthreads();
  {
    const int k2o = lo*4, k1o = hi*4;
    float br[4][4] = {}, bi[4][4] = {};
    for (int h = 0; h < 64; ++h){
      float er[4], ei[4], cr[4], ci[4];
      ld4a(er, tfr + h*64 + k1o);
      ld4a(ei, tfi + h*64 + k1o);
      ld4a(cr, &Tre[h][k2o]);
      ld4a(ci, &Tim[h][k2o]);
      #pragma unroll
      for (int i = 0; i < 4; ++i)
        #pragma unroll
        for (int j = 0; j < 4; ++j){
          br[i][j] += er[i]*cr[j] - ei[i]*ci[j];
          bi[i][j] += er[i]*ci[j] + ei[i]*cr[j];
        }
    }
    #pragma unroll
    for (int i = 0; i < 4; ++i){
      st4b(Frb + bc*4096 + (k1o+i)*64 + k2o, br[i]);
      st4b(Fib + bc*4096 + (k1o+i)*64 + k2o, bi[i]);
    }
  }
}

// ===================== row norms =====================
__global__ __launch_bounds__(256) void k_norms(const u16* __restrict__ Frb, const u16* __restrict__ Fib,
                                               float* __restrict__ norms){
  const int bc = blockIdx.x, t = threadIdx.x;
  const u16* pr = Frb + bc*4096;
  const u16* pi = Fib + bc*4096;
  float s = 0.f;
  for (int i = t*4; i < 4096; i += 1024){
    float a[4], b[4];
    ld4b(a, pr + i); ld4b(b, pi + i);
    #pragma unroll
    for (int k = 0; k < 4; ++k) s = fmaf(a[k],a[k],fmaf(b[k],b[k],s));
  }
  #pragma unroll
  for (int off = 32; off > 0; off >>= 1) s += __shfl_down(s, off, 64);
  __shared__ float red[4];
  if ((t & 63) == 0) red[t >> 6] = s;
  __syncthreads();
  if (t == 0){
    float tot = red[0]+red[1]+red[2]+red[3];
    norms[bc] = fmaxf(sqrtf(tot), 1e-12f);
  }
}

// ===================== attention: Gram + dual softmax + fold c-axis ifft =====================
__global__ __launch_bounds__(256) void k_attn(const u16* __restrict__ Frb, const u16* __restrict__ Fib,
                                              const float* __restrict__ norms, const float* __restrict__ prm,
                                              float* __restrict__ wsM){
  __shared__ float SR[16][260];
  __shared__ float SI[16][260];
  __shared__ float AR[16][17], AI[16][17];
  const int bh = blockIdx.x;
  const int b = bh >> 3, h = bh & 7;
  const int t = threadIdx.x;
  const int tile = t & 15, part = t >> 4;
  const int i0 = (tile >> 2)*4, j0 = (tile & 3)*4;
  const u16* fr = Frb + (b*128 + h*16)*4096;
  const u16* fi = Fib + (b*128 + h*16)*4096;
  float gr[4][4] = {}, gi[4][4] = {};
  for (int nc = 0; nc < 16; ++nc){
    const int nb = nc*256;
    for (int idx = t; idx < 1024; idx += 256){
      int r = idx >> 6, col = (idx & 63)*4;
      float tmp[4];
      ld4b(tmp, fr + r*4096 + nb + col); st4(&SR[r][col], tmp);
      ld4b(tmp, fi + r*4096 + nb + col); st4(&SI[r][col], tmp);
    }
    __syncthreads();
    #pragma unroll
    for (int s = 0; s < 4; ++s){
      const int nn = part*16 + s*4;
      float arr[4][4], ari[4][4], brr[4][4], bri[4][4];
      #pragma unroll
      for (int i = 0; i < 4; ++i){
        ld4a(arr[i], &SR[i0+i][nn]);
        ld4a(ari[i], &SI[i0+i][nn]);
        ld4a(brr[i], &SR[j0+i][nn]);
        ld4a(bri[i], &SI[j0+i][nn]);
      }
      #pragma unroll
      for (int i = 0; i < 4; ++i)
        #pragma unroll
        for (int j = 0; j < 4; ++j)
          #pragma unroll
          for (int m = 0; m < 4; ++m){
            gr[i][j] += arr[i][m]*brr[j][m] - ari[i][m]*bri[j][m];
            gi[i][j] += arr[i][m]*bri[j][m] + ari[i][m]*brr[j][m];
          }
    }
    __syncthreads();
  }
  float* redR = &SR[0][0];
  float* redI = &SI[0][0];
  #pragma unroll
  for (int e = 0; e < 16; ++e){
    redR[t*16 + e] = gr[e>>2][e&3];
    redI[t*16 + e] = gi[e>>2][e&3];
  }
  __syncthreads();
  {
    const int tile2 = t >> 4, e2 = t & 15;
    float sr = 0.f, si = 0.f;
    for (int p = 0; p < 16; ++p){
      sr += redR[(p*16 + tile2)*16 + e2];
      si += redI[(p*16 + tile2)*16 + e2];
    }
    const int ii = (tile2 >> 2)*4 + (e2 >> 2);
    const int jj = (tile2 & 3)*4 + (e2 & 3);
    const float tm = prm[P_TEMP + h];
    const float sc = tm / (norms[b*128 + h*16 + ii] * norms[b*128 + h*16 + jj]);
    AR[ii][jj] = sr*sc;
    AI[ii][jj] = si*sc;
  }
  __syncthreads();
  if (t < 32){
    float* row = (t < 16) ? AR[t & 15] : AI[t & 15];
    float mx = row[0];
    for (int j2 = 1; j2 < 16; ++j2) mx = fmaxf(mx, row[j2]);
    float s = 0.f, e[16];
    for (int j2 = 0; j2 < 16; ++j2){ e[j2] = expf(row[j2] - mx); s += e[j2]; }
    float inv = 1.f/s;
    for (int j2 = 0; j2 < 16; ++j2) row[j2] = e[j2]*inv;
  }
  __syncthreads();
  {
    const int mi = t >> 4, mj = t & 15;
    float mr = 0.f, mim = 0.f;
    #pragma unroll
    for (int p = 0; p < 16; ++p){
      float sv, cv;
      sincospif((float)((mi*p) & 15)/8.0f, &sv, &cv);
      const float arv = AR[p][mj], aiv = AI[p][mj];
      mr  += cv*arv - sv*aiv;
      mim += cv*aiv + sv*arv;
    }
    wsM[bh*512 + t*2]     = mr*(1.f/16.f);
    wsM[bh*512 + t*2 + 1] = mim*(1.f/16.f);
  }
}

// ===================== gating MLP -> g plane (bf16) =====================
__global__ __launch_bounds__(256) void k_gate(const u16* __restrict__ Frb,
                                              const float* __restrict__ prm,
                                              u16* __restrict__ g){
  __shared__ float W1T[128][8];
  __shared__ float W2[128][8];
  __shared__ float B1v[8], S1v[8], BB1v[8];
  __shared__ float B2v[128];
  const int t = threadIdx.x;
  for (int i = t; i < 1024; i += 256){
    W1T[i & 127][i >> 7] = prm[P_W1 + i];
    W2[i >> 3][i & 7]    = prm[P_W2 + i];
  }
  if (t < 8){ B1v[t] = prm[P_B1+t]; S1v[t] = prm[P_S1+t]; BB1v[t] = prm[P_BB1+t]; }
  if (t < 128) B2v[t] = prm[P_B2+t];
  __syncthreads();
  const int pix = blockIdx.x*256 + t;
  const int b = pix >> 12, n = pix & 4095;
  const u16* fr = Frb + b*128*4096 + n;
  float q[8] = {};
  for (int c = 0; c < 128; ++c){
    const float v = bu2f(fr[c*4096]);
    float wa[4], wb[4];
    ld4a(wa, &W1T[c][0]); ld4a(wb, &W1T[c][4]);
    #pragma unroll
    for (int k = 0; k < 4; ++k){ q[k] = fmaf(wa[k], v, q[k]); q[4+k] = fmaf(wb[k], v, q[4+k]); }
  }
  float qa[8];
  #pragma unroll
  for (int k = 0; k < 8; ++k)
    qa[k] = fmaxf(fmaf(q[k] + B1v[k], S1v[k], BB1v[k]), 0.f);
  u16* grow = g + b*128*4096 + n;
  for (int c = 0; c < 128; ++c){
    float wa[4], wb[4];
    ld4a(wa, &W2[c][0]); ld4a(wb, &W2[c][4]);
    float acc = B2v[c];
    #pragma unroll
    for (int k = 0; k < 4; ++k) acc += wa[k]*qa[k] + wb[k]*qa[4+k];
    grow[c*4096] = f2bu(1.f/(1.f + expf(-acc)));
  }
}

// ===================== out_l = |ifft2(g*F)| + x  (channels 128..255), f32 out =====================
__global__ __launch_bounds__(256) void k_outl(const u16* __restrict__ Frb, const u16* __restrict__ Fib,
                                              const u16* __restrict__ g, const void* __restrict__ x,
                                              float* __restrict__ out, const float* __restrict__ ws,
                                              const int* __restrict__ flg){
  __shared__ float Tre[64][68], Tim[64][68];
  const int bc = blockIdx.x, t = threadIdx.x;
  const int b = bc >> 7, c = bc & 127;
  const int lo = t & 15, hi = t >> 4;
  const int f32m = __builtin_amdgcn_readfirstlane(*flg);
  const float* tir = ws + TABIF_RE;
  const float* tii = ws + TABIF_IM;
  const u16* pg = g   + bc*4096;
  const u16* pr = Frb + bc*4096;
  const u16* pi = Fib + bc*4096;
  {
    const int k0 = lo*4, h0 = hi*4;
    float ar[4][4] = {}, ai[4][4] = {};
    for (int w4 = 0; w4 < 64; w4 += 4){
      float gv[4][4], fre[4][4], fim[4][4];
      #pragma unroll
      for (int i = 0; i < 4; ++i){
        ld4b(gv[i],  pg + (h0+i)*64 + w4);
        ld4b(fre[i], pr + (h0+i)*64 + w4);
        ld4b(fim[i], pi + (h0+i)*64 + w4);
      }
      #pragma unroll
      for (int u = 0; u < 4; ++u){
        float er[4], ei[4];
        ld4a(er, tir + (w4+u)*64 + k0);
        ld4a(ei, tii + (w4+u)*64 + k0);
        #pragma unroll
        for (int i = 0; i < 4; ++i){
          const float prv = gv[i][u]*fre[i][u];
          const float piv = gv[i][u]*fim[i][u];
          #pragma unroll
          for (int j = 0; j < 4; ++j){
            ar[i][j] += prv*er[j] - piv*ei[j];
            ai[i][j] += prv*ei[j] + piv*er[j];
          }
        }
      }
    }
    #pragma unroll
    for (int i = 0; i < 4; ++i){ st4(&Tre[h0+i][k0], ar[i]); st4(&Tim[h0+i][k0], ai[i]); }
  }
  __syncthreads();
  {
    const int k2o = lo*4, k1o = hi*4;
    float yr[4][4] = {}, yi[4][4] = {};
    for (int h = 0; h < 64; ++h){
      float er[4], ei[4], cr[4], ci[4];
      ld4a(er, tir + h*64 + k1o);
      ld4a(ei, tii + h*64 + k1o);
      ld4a(cr, &Tre[h][k2o]);
      ld4a(ci, &Tim[h][k2o]);
      #pragma unroll
      for (int i = 0; i < 4; ++i)
        #pragma unroll
        for (int j = 0; j < 4; ++j){
          yr[i][j] += er[i]*cr[j] - ei[i]*ci[j];
          yi[i][j] += er[i]*ci[j] + ei[i]*cr[j];
        }
    }
    const int base = (b*256 + 128 + c)*4096;
    #pragma unroll
    for (int i = 0; i < 4; ++i){
      const int o = base + (k1o+i)*64 + k2o;
      float xr[4];
      if (f32m) ld4a(xr, (const float*)x + o); else ld4b(xr, (const u16*)x + o);
      float ov[4];
      #pragma unroll
      for (int j = 0; j < 4; ++j)
        ov[j] = sqrtf(yr[i][j]*yr[i][j] + yi[i][j]*yi[i][j]) + xr[j];
      st4(out + o, ov);
    }
  }
}

// ===================== 4096-pt IFFT per (b,c) row, four-step, in place =====================
__global__ __launch_bounds__(256) void k_ifft4096(u16* __restrict__ Frb, u16* __restrict__ Fib,
                                                  const float* __restrict__ ws){
  __shared__ float Cre[64][68], Cim[64][68];
  const int bc = blockIdx.x, t = threadIdx.x;
  const int lo = t & 15, hi = t >> 4;
  const float* tir = ws + TABIF_RE;
  const float* tii = ws + TABIF_IM;
  const float* twr = ws + TABTW_RE;
  const float* twi = ws + TABTW_IM;
  u16* fr = Frb + bc*4096;
  u16* fi = Fib + bc*4096;
  {
    const int k10 = lo*4, n20 = hi*4;
    float ar[4][4] = {}, ai[4][4] = {};
    for (int n1 = 0; n1 < 64; ++n1){
      float er[4], ei[4], xr[4], xi[4];
      ld4a(er, tir + n1*64 + k10);
      ld4a(ei, tii + n1*64 + k10);
      ld4b(xr, fr + n1*64 + n20);
      ld4b(xi, fi + n1*64 + n20);
      #pragma unroll
      for (int i = 0; i < 4; ++i)
        #pragma unroll
        for (int j = 0; j < 4; ++j){
          ar[i][j] += er[i]*xr[j] - ei[i]*xi[j];
          ai[i][j] += er[i]*xi[j] + ei[i]*xr[j];
        }
    }
    float crT[4][4], ciT[4][4];
    #pragma unroll
    for (int i = 0; i < 4; ++i){
      float wr[4], wi[4];
      ld4a(wr, twr + (k10+i)*64 + n20);
      ld4a(wi, twi + (k10+i)*64 + n20);
      #pragma unroll
      for (int j = 0; j < 4; ++j){
        crT[j][i] = ar[i][j]*wr[j] - ai[i][j]*wi[j];
        ciT[j][i] = ar[i][j]*wi[j] + ai[i][j]*wr[j];
      }
    }
    #pragma unroll
    for (int j = 0; j < 4; ++j){
      st4(&Cre[n20+j][k10], crT[j]);
      st4(&Cim[n20+j][k10], ciT[j]);
    }
  }
  __syncthreads();
  {
    const int k1o = lo*4, k2o = hi*4;
    float dr[4][4] = {}, di[4][4] = {};
    for (int n2 = 0; n2 < 64; ++n2){
      float er[4], ei[4], cr[4], ci[4];
      ld4a(er, tir + n2*64 + k2o);
      ld4a(ei, tii + n2*64 + k2o);
      ld4a(cr, &Cre[n2][k1o]);
      ld4a(ci, &Cim[n2][k1o]);
      #pragma unroll
      for (int i = 0; i < 4; ++i)
        #pragma unroll
        for (int j = 0; j < 4; ++j){
          dr[i][j] += cr[i]*er[j] - ci[i]*ei[j];
          di[i][j] += cr[i]*ei[j] + ci[i]*er[j];
        }
    }
    #pragma unroll
    for (int j = 0; j < 4; ++j){
      float o_r[4], o_i[4];
      #pragma unroll
      for (int i = 0; i < 4; ++i){ o_r[i] = dr[i][j]; o_i[i] = di[i][j]; }
      st4b(fr + (k2o+j)*64 + k1o, o_r);
      st4b(fi + (k2o+j)*64 + k1o, o_i);
    }
  }
}

// ===================== out_f = |M @ Z| + x  (channels 0..127), f32 out =====================
__global__ __launch_bounds__(256) void k_outf(const u16* __restrict__ Zr, const u16* __restrict__ Zi,
                                              const float* __restrict__ wsM, const void* __restrict__ x,
                                              float* __restrict__ out, const int* __restrict__ flg){
  __shared__ float MreT[16][20], MimT[16][20];
  const int gb = blockIdx.x;
  const int bh = gb & 127, nch = gb >> 7;
  const int b = bh >> 3, h = bh & 7;
  const int t = threadIdx.x;
  const int f32m = __builtin_amdgcn_readfirstlane(*flg);
  {
    const int i = t >> 4, j = t & 15;
    MreT[j][i] = wsM[bh*512 + t*2];
    MimT[j][i] = wsM[bh*512 + t*2 + 1];
  }
  __syncthreads();
  const int i0 = (t & 3)*4;
  const int nn = nch*256 + (t >> 2)*4;
  const u16* zr = Zr + (b*128 + h*16)*4096 + nn;
  const u16* zi = Zi + (b*128 + h*16)*4096 + nn;
  float accr[4][4] = {}, acci[4][4] = {};
  #pragma unroll
  for (int j = 0; j < 16; ++j){
    float mr[4], mi[4], vr[4], vi[4];
    ld4a(mr, &MreT[j][i0]);
    ld4a(mi, &MimT[j][i0]);
    ld4b(vr, zr + j*4096);
    ld4b(vi, zi + j*4096);
    #pragma unroll
    for (int i = 0; i < 4; ++i)
      #pragma unroll
      for (int n = 0; n < 4; ++n){
        accr[i][n] += mr[i]*vr[n] - mi[i]*vi[n];
        acci[i][n] += mr[i]*vi[n] + mi[i]*vr[n];
      }
  }
  #pragma unroll
  for (int i = 0; i < 4; ++i){
    const int o = (b*256 + h*16 + i0 + i)*4096 + nn;
    float xr[4];
    if (f32m) ld4a(xr, (const float*)x + o); else ld4b(xr, (const u16*)x + o);
    float ov[4];
    #pragma unroll
    for (int n = 0; n < 4; ++n)
      ov[n] = sqrtf(accr[i][n]*accr[i][n] + acci[i][n]*acci[i][n]) + xr[n];
    st4(out + o, ov);
  }
}

// ===================== launch =====================
extern "C" void kernel_launch(void* const* d_in, const int* in_sizes, int n_in,
                              void* d_out, int out_size, void* d_ws, size_t ws_size,
                              hipStream_t stream) {
  const void* x        = d_in[0];
  const void* conv2_w  = d_in[1];
  const void* conv2_b  = d_in[2];
  const void* bn2_s    = d_in[3];
  const void* bn2_b    = d_in[4];
  const void* temp     = d_in[5];
  const void* w1_w     = d_in[6];
  const void* w1_b     = d_in[7];
  const void* bnw_s    = d_in[8];
  const void* bnw_b    = d_in[9];
  const void* w2_w     = d_in[10];
  const void* w2_b     = d_in[11];
  float* out = (float*)d_out;
  float* wsf = (float*)d_ws;

  if (ws_size < (size_t)(F32_END*4) + 3u*(size_t)BPLANE*2u) return;

  int* flag = (int*)(wsf + FLAG_OFF);
  float* prm = wsf + PRM_OFF;
  u16* wT2 = (u16*)(wsf + WT_OFF);
  u16* wsb = (u16*)(wsf + F32_END);
  u16* Frb = wsb;
  u16* Fib = wsb + BPLANE;
  u16* xt  = wsb;              // x_t aliases Frb+Fib (dead before k_fft2 writes them)
  u16* Ab  = wsb + 2*BPLANE;   // conv output; later aliased by g
  u16* g   = Ab;

  k_detect<<<1, 64, 0, stream>>>((const u16*)x, flag);
  k_tables<<<16, 256, 0, stream>>>(wsf);
  k_pack<<<1, 256, 0, stream>>>(conv2_b, bn2_s, bn2_b, temp, w1_w, w1_b, bnw_s, bnw_b,
                                w2_w, w2_b, flag, prm);
  k_wprep2<<<1152, 256, 0, stream>>>(conv2_w, wT2, prm, flag);
  k_trans<<<1024, 256, 0, stream>>>(x, xt, flag);
  k_cmm<<<256, 256, 0, stream>>>(xt, wT2, prm, Ab);
  k_fft2<<<2048, 256, 0, stream>>>(Ab, Frb, Fib, wsf);
  k_norms<<<2048, 256, 0, stream>>>(Frb, Fib, wsf + NORMS_OFF);
  k_attn<<<128, 256, 0, stream>>>(Frb, Fib, wsf + NORMS_OFF, prm, wsf + MMAT_OFF);
  k_gate<<<256, 256, 0, stream>>>(Frb, prm, g);
  k_outl<<<2048, 256, 0, stream>>>(Frb, Fib, g, x, out, wsf, flag);
  k_ifft4096<<<2048, 256, 0, stream>>>(Frb, Fib, wsf);
  k_outf<<<2048, 256, 0, stream>>>(Frb, Fib, wsf + MMAT_OFF, x, out, flag);
}

// Round 5
// 564.000 us; speedup vs baseline: 2.5262x; 1.3986x over previous
//
#include <hip/hip_runtime.h>

typedef unsigned short u16;
typedef short short8 __attribute__((ext_vector_type(8)));
typedef float f32x4 __attribute__((ext_vector_type(4)));

#define MF(a,b,c) __builtin_amdgcn_mfma_f32_16x16x32_bf16(a,b,c,0,0,0)

// ---------- bf16 helpers ----------
__device__ __forceinline__ float bu2f(u16 u){
  return __uint_as_float(((unsigned int)u) << 16);
}
__device__ __forceinline__ u16 f2bu(float f){
  unsigned int b = __float_as_uint(f);
  unsigned int r = (b + 0x7FFFu + ((b >> 16) & 1u)) >> 16;  // RNE
  return (u16)r;
}
__device__ __forceinline__ void ld4a(float* d, const float* p){
  float4 v = *(const float4*)p;
  d[0]=v.x; d[1]=v.y; d[2]=v.z; d[3]=v.w;
}
__device__ __forceinline__ void st4(float* p, const float* s){
  *(float4*)p = make_float4(s[0], s[1], s[2], s[3]);
}
__device__ __forceinline__ void ld4b(float* d, const u16* p){
  ushort4 v = *(const ushort4*)p;
  d[0]=bu2f(v.x); d[1]=bu2f(v.y); d[2]=bu2f(v.z); d[3]=bu2f(v.w);
}
__device__ __forceinline__ void st4b(u16* p, const float* s){
  ushort4 v;
  v.x=f2bu(s[0]); v.y=f2bu(s[1]); v.z=f2bu(s[2]); v.w=f2bu(s[3]);
  *(ushort4*)p = v;
}
__device__ __forceinline__ ushort4 pk4(f32x4 v){
  ushort4 u; u.x=f2bu(v[0]); u.y=f2bu(v[1]); u.z=f2bu(v[2]); u.w=f2bu(v[3]); return u;
}
__device__ __forceinline__ short8 mulpk(short8 g, short8 f){
  short8 o;
  #pragma unroll
  for (int e = 0; e < 8; ++e)
    o[e] = (short)f2bu(bu2f((u16)g[e])*bu2f((u16)f[e]));
  return o;
}

// ---------- workspace layout ----------
#define TABF_RE   0
#define TABF_IM   4096
#define TABIF_RE  8192
#define TABIF_IM  12288
#define TABTW_RE  16384      // exp(+2pi i k1*n2/4096) f32 [k1][n2]
#define TABTW_IM  20480
#define NORMS_OFF 24576
#define MMAT_OFF  26624
#define FLAG_OFF  92160
#define PRM_OFF   92224
#define WT_OFF    94848      // wT2 bf16 conv weights (294912 u16)
#define DFT16_OFF 242304     // bf16 DFT matrices: EFr,EFi,EIr,EIi (4*4096 u16)
#define F32_END   389760
// params sub-offsets:
#define P_CB   0
#define P_BNS  128
#define P_BNB  256
#define P_TEMP 384
#define P_W1   400
#define P_B1   1424
#define P_S1   1432
#define P_BB1  1440
#define P_W2   1456
#define P_B2   2480
// bf16 region:
#define BPLANE    8388608
// x_t aliases Frb+Fib (dead before k_fft2_m writes them); A/g at 2*BPLANE.

// ===================== input dtype detection =====================
__global__ void k_detect(const u16* __restrict__ xv, int* __restrict__ flag){
  const int t = threadIdx.x;
  int huge = 0;
  for (int i = 0; i < 16; ++i){
    u16 u = xv[(t*16 + i)*2];
    int e = (u >> 7) & 0xFF;
    huge += (e >= 0xC0) ? 1 : 0;
  }
  #pragma unroll
  for (int off = 32; off > 0; off >>= 1) huge += __shfl_down(huge, off, 64);
  if (t == 0) flag[0] = (huge >= 8) ? 1 : 0;
}

// ===================== tables =====================
__global__ void k_tables(float* ws){
  int idx = blockIdx.x*256 + threadIdx.x;
  int j = idx >> 6, k = idx & 63;
  int jk = j*k;
  float s, c;
  sincospif(-(float)(jk & 63)/32.0f, &s, &c);
  ws[TABF_RE+idx] = c; ws[TABF_IM+idx] = s;
  sincospif((float)(jk & 63)/32.0f, &s, &c);
  ws[TABIF_RE+idx] = c*(1.f/64.f); ws[TABIF_IM+idx] = s*(1.f/64.f);
  sincospif((float)jk/2048.0f, &s, &c);
  ws[TABTW_RE+idx] = c; ws[TABTW_IM+idx] = s;
}

// bf16 DFT matrices (fragment-ready row-major; E is symmetric)
__global__ void k_dftprep(u16* __restrict__ m){
  int idx = blockIdx.x*256 + threadIdx.x;   // 0..4095
  int j = idx >> 6, k = idx & 63;
  int jk = (j*k) & 63;
  float s, c;
  sincospif(-(float)jk/32.0f, &s, &c);
  m[idx]        = f2bu(c);
  m[4096+idx]   = f2bu(s);
  sincospif((float)jk/32.0f, &s, &c);
  m[8192+idx]   = f2bu(c*(1.f/64.f));
  m[12288+idx]  = f2bu(s*(1.f/64.f));
}

// ===================== pack small params -> f32 =====================
__global__ void k_pack(const void* cb, const void* bns, const void* bnb, const void* temp,
                       const void* w1, const void* b1, const void* s1, const void* bb1,
                       const void* w2, const void* b2,
                       const int* __restrict__ flg, float* __restrict__ P){
  const int t = threadIdx.x;
  const int f32 = *flg;
  if (f32){
    for (int i = t; i < 128; i += 256){
      P[P_CB+i]  = ((const float*)cb)[i];
      P[P_BNS+i] = ((const float*)bns)[i];
      P[P_BNB+i] = ((const float*)bnb)[i];
      P[P_B2+i]  = ((const float*)b2)[i];
    }
    for (int i = t; i < 1024; i += 256){
      P[P_W1+i] = ((const float*)w1)[i];
      P[P_W2+i] = ((const float*)w2)[i];
    }
    if (t < 8){
      P[P_TEMP+t] = ((const float*)temp)[t];
      P[P_B1+t]   = ((const float*)b1)[t];
      P[P_S1+t]   = ((const float*)s1)[t];
      P[P_BB1+t]  = ((const float*)bb1)[t];
    }
  } else {
    for (int i = t; i < 128; i += 256){
      P[P_CB+i]  = bu2f(((const u16*)cb)[i]);
      P[P_BNS+i] = bu2f(((const u16*)bns)[i]);
      P[P_BNB+i] = bu2f(((const u16*)bnb)[i]);
      P[P_B2+i]  = bu2f(((const u16*)b2)[i]);
    }
    for (int i = t; i < 1024; i += 256){
      P[P_W1+i] = bu2f(((const u16*)w1)[i]);
      P[P_W2+i] = bu2f(((const u16*)w2)[i]);
    }
    if (t < 8){
      P[P_TEMP+t] = bu2f(((const u16*)temp)[t]);
      P[P_B1+t]   = bu2f(((const u16*)b1)[t]);
      P[P_S1+t]   = bu2f(((const u16*)s1)[t]);
      P[P_BB1+t]  = bu2f(((const u16*)bb1)[t]);
    }
  }
}

// ===================== weight prep for MFMA conv =====================
__global__ void k_wprep2(const void* __restrict__ w, u16* __restrict__ wT2,
                         const float* __restrict__ prm, const int* __restrict__ flg){
  const int f32 = *flg;
  int U = blockIdx.x*256 + threadIdx.x;
  if (U < 294912){
    int j = U & 7;
    int E = U >> 3;
    int n = E & 127;
    int o = (E >> 7) & 3;
    int tc = E >> 9;
    int chunk = tc & 7, tap = tc >> 3;
    int c = chunk*32 + o*8 + j;
    int src = n*2304 + c*9 + tap;
    float v = f32 ? ((const float*)w)[src] : bu2f(((const u16*)w)[src]);
    wT2[U] = f2bu(v * prm[P_BNS + n]);
  }
}

// ===================== x transpose: NCHW -> [b][h][w][c] bf16 =====================
__global__ __launch_bounds__(256) void k_trans(const void* __restrict__ x, u16* __restrict__ xt,
                                               const int* __restrict__ flg){
  __shared__ u16 L[256*66];
  const int t = threadIdx.x;
  const int b = blockIdx.x >> 6, h = blockIdx.x & 63;
  const int f32m = __builtin_amdgcn_readfirstlane(*flg);
  if (f32m){
    const float* xf = (const float*)x;
    for (int i = t; i < 16384; i += 256){
      int c = i >> 6, w = i & 63;
      L[c*66 + w] = f2bu(xf[((b*256 + c)*64 + h)*64 + w]);
    }
  } else {
    const u16* xb = (const u16*)x;
    for (int i = t; i < 16384; i += 256){
      int c = i >> 6, w = i & 63;
      L[c*66 + w] = xb[((b*256 + c)*64 + h)*64 + w];
    }
  }
  __syncthreads();
  u16* dst = xt + ((b*64 + h)*64)*256;
  for (int j = t; j < 16384; j += 256){
    int w = j >> 8, c = j & 255;
    dst[w*256 + c] = L[c*66 + w];
  }
}

// ===================== MFMA implicit-GEMM conv + BN + ReLU =====================
__global__ __launch_bounds__(256) void k_cmm(const u16* __restrict__ xt, const u16* __restrict__ wT2,
                                             const float* __restrict__ prm, u16* __restrict__ A){
  __shared__ uint4 sm4[4096];
  const int t = threadIdx.x;
  const int bb = blockIdx.x >> 4;
  const int mtile = blockIdx.x & 15;
  const int h0 = mtile*4;
  const int lane = t & 63, wave = t >> 6;
  const int quad = lane >> 4, lr = lane & 15;

  f32x4 acc[4][8];
  #pragma unroll
  for (int mi = 0; mi < 4; ++mi)
    #pragma unroll
    for (int nt = 0; nt < 8; ++nt)
      acc[mi][nt] = (f32x4){0.f,0.f,0.f,0.f};

  const u16* smB = (const u16*)sm4;
  const short8 zz = {0,0,0,0,0,0,0,0};

  for (int tap = 0; tap < 9; ++tap){
    const int ky = tap/3, kx = tap - ky*3;
    __syncthreads();
    {
      const uint4* src = (const uint4*)(wT2 + tap*32768);
      #pragma unroll
      for (int i = 0; i < 16; ++i) sm4[t + 256*i] = src[t + 256*i];
    }
    __syncthreads();

    const int hg = h0 + wave + 3*ky - 3;
    const bool hok = ((unsigned)hg < 64u);
    const u16* abase = xt + ((bb*64 + hg)*64)*256 + quad*8;

    for (int chunk = 0; chunk < 8; ++chunk){
      short8 av[4];
      #pragma unroll
      for (int mi = 0; mi < 4; ++mi){
        const int wg = mi*16 + lr + 3*kx - 3;
        short8 v = zz;
        if (hok && ((unsigned)wg < 64u))
          v = *(const short8*)(abase + wg*256 + chunk*32);
        av[mi] = v;
      }
      short8 bv[8];
      #pragma unroll
      for (int nt = 0; nt < 8; ++nt)
        bv[nt] = *(const short8*)(smB + (chunk*512 + quad*128 + nt*16 + lr)*8);
      #pragma unroll
      for (int mi = 0; mi < 4; ++mi)
        #pragma unroll
        for (int nt = 0; nt < 8; ++nt)
          acc[mi][nt] = MF(av[mi], bv[nt], acc[mi][nt]);
    }
  }

  float* C = (float*)sm4;
  u16* outb = A + (bb*128)*4096 + mtile*256;
  __syncthreads();
  for (int nt = 0; nt < 8; ++nt){
    #pragma unroll
    for (int mi = 0; mi < 4; ++mi)
      #pragma unroll
      for (int r = 0; r < 4; ++r){
        int m = wave*64 + mi*16 + quad*4 + r;
        C[lr*261 + m] = acc[mi][nt][r];
      }
    __syncthreads();
    #pragma unroll
    for (int dd = 0; dd < 16; ++dd){
      int d = nt*16 + dd;
      float bi = prm[P_CB + d]*prm[P_BNS + d] + prm[P_BNB + d];
      float v = fmaxf(C[dd*261 + t] + bi, 0.f);
      outb[d*4096 + t] = f2bu(v);
    }
    __syncthreads();
  }
}

// ===================== fft2 via MFMA: F = E*img*E per (b,c) =====================
__global__ __launch_bounds__(256) void k_fft2_m(const u16* __restrict__ A, u16* __restrict__ Frb,
                                                u16* __restrict__ Fib, const u16* __restrict__ dft){
  __shared__ __align__(16) u16 TTr[64*72], TTi[64*72];
  const int bc = blockIdx.x, t = threadIdx.x;
  const int lane = t & 63, wave = t >> 6;
  const int quad = lane >> 4, lr = lane & 15;
  const u16* EFr = dft;
  const u16* EFi = dft + 4096;
  const u16* img = A + bc*4096;
  // pass1: T[h][k2] = sum_w img[h][w] E[k2][w]; store T^T[k2][h] (k2-tile = wave)
  #pragma unroll
  for (int mi = 0; mi < 4; ++mi){
    f32x4 ar = {0.f,0.f,0.f,0.f}, ai = {0.f,0.f,0.f,0.f};
    #pragma unroll
    for (int ks = 0; ks < 2; ++ks){
      short8 av = *(const short8*)(img + (mi*16+lr)*64 + ks*32 + quad*8);
      short8 br = *(const short8*)(EFr + (wave*16+lr)*64 + ks*32 + quad*8);
      short8 bi = *(const short8*)(EFi + (wave*16+lr)*64 + ks*32 + quad*8);
      ar = MF(av, br, ar); ai = MF(av, bi, ai);
    }
    // D[m=h=mi*16+quad*4+r][n=k2=wave*16+lr]
    *(ushort4*)(TTr + (wave*16+lr)*72 + mi*16 + quad*4) = pk4(ar);
    *(ushort4*)(TTi + (wave*16+lr)*72 + mi*16 + quad*4) = pk4(ai);
  }
  __syncthreads();
  // pass2: F^T[k2][k1] = sum_h T^T[k2][h] E[k1][h]  (k2-tile = wave)
  #pragma unroll
  for (int nt = 0; nt < 4; ++nt){
    f32x4 a1={0.f,0.f,0.f,0.f}, a2={0.f,0.f,0.f,0.f}, a3={0.f,0.f,0.f,0.f}, a4={0.f,0.f,0.f,0.f};
    #pragma unroll
    for (int ks = 0; ks < 2; ++ks){
      short8 tr = *(const short8*)(TTr + (wave*16+lr)*72 + ks*32 + quad*8);
      short8 ti = *(const short8*)(TTi + (wave*16+lr)*72 + ks*32 + quad*8);
      short8 br = *(const short8*)(EFr + (nt*16+lr)*64 + ks*32 + quad*8);
      short8 bi = *(const short8*)(EFi + (nt*16+lr)*64 + ks*32 + quad*8);
      a1 = MF(tr, br, a1); a2 = MF(ti, bi, a2);
      a3 = MF(tr, bi, a3); a4 = MF(ti, br, a4);
    }
    f32x4 fr, fi;
    #pragma unroll
    for (int r = 0; r < 4; ++r){ fr[r] = a1[r]-a2[r]; fi[r] = a3[r]+a4[r]; }
    // D[m=k2=wave*16+quad*4+r][n=k1=nt*16+lr]; flat = k1*64 + k2
    const int flat = (nt*16+lr)*64 + wave*16 + quad*4;
    *(ushort4*)(Frb + bc*4096 + flat) = pk4(fr);
    *(ushort4*)(Fib + bc*4096 + flat) = pk4(fi);
  }
}

// ===================== row norms =====================
__global__ __launch_bounds__(256) void k_norms(const u16* __restrict__ Frb, const u16* __restrict__ Fib,
                                               float* __restrict__ norms){
  const int bc = blockIdx.x, t = threadIdx.x;
  const u16* pr = Frb + bc*4096;
  const u16* pi = Fib + bc*4096;
  float s = 0.f;
  for (int i = t*4; i < 4096; i += 1024){
    float a[4], b[4];
    ld4b(a, pr + i); ld4b(b, pi + i);
    #pragma unroll
    for (int k = 0; k < 4; ++k) s = fmaf(a[k],a[k],fmaf(b[k],b[k],s));
  }
  #pragma unroll
  for (int off = 32; off > 0; off >>= 1) s += __shfl_down(s, off, 64);
  __shared__ float red[4];
  if ((t & 63) == 0) red[t >> 6] = s;
  __syncthreads();
  if (t == 0){
    float tot = red[0]+red[1]+red[2]+red[3];
    norms[bc] = fmaxf(sqrtf(tot), 1e-12f);
  }
}

// ===================== attention: Gram + dual softmax + fold c-axis ifft =====================
__global__ __launch_bounds__(256) void k_attn(const u16* __restrict__ Frb, const u16* __restrict__ Fib,
                                              const float* __restrict__ norms, const float* __restrict__ prm,
                                              float* __restrict__ wsM){
  __shared__ float SR[16][260];
  __shared__ float SI[16][260];
  __shared__ float AR[16][17], AI[16][17];
  const int bh = blockIdx.x;
  const int b = bh >> 3, h = bh & 7;
  const int t = threadIdx.x;
  const int tile = t & 15, part = t >> 4;
  const int i0 = (tile >> 2)*4, j0 = (tile & 3)*4;
  const u16* fr = Frb + (b*128 + h*16)*4096;
  const u16* fi = Fib + (b*128 + h*16)*4096;
  float gr[4][4] = {}, gi[4][4] = {};
  for (int nc = 0; nc < 16; ++nc){
    const int nb = nc*256;
    for (int idx = t; idx < 1024; idx += 256){
      int r = idx >> 6, col = (idx & 63)*4;
      float tmp[4];
      ld4b(tmp, fr + r*4096 + nb + col); st4(&SR[r][col], tmp);
      ld4b(tmp, fi + r*4096 + nb + col); st4(&SI[r][col], tmp);
    }
    __syncthreads();
    #pragma unroll
    for (int s = 0; s < 4; ++s){
      const int nn = part*16 + s*4;
      float arr[4][4], ari[4][4], brr[4][4], bri[4][4];
      #pragma unroll
      for (int i = 0; i < 4; ++i){
        ld4a(arr[i], &SR[i0+i][nn]);
        ld4a(ari[i], &SI[i0+i][nn]);
        ld4a(brr[i], &SR[j0+i][nn]);
        ld4a(bri[i], &SI[j0+i][nn]);
      }
      #pragma unroll
      for (int i = 0; i < 4; ++i)
        #pragma unroll
        for (int j = 0; j < 4; ++j)
          #pragma unroll
          for (int m = 0; m < 4; ++m){
            gr[i][j] += arr[i][m]*brr[j][m] - ari[i][m]*bri[j][m];
            gi[i][j] += arr[i][m]*bri[j][m] + ari[i][m]*brr[j][m];
          }
    }
    __syncthreads();
  }
  float* redR = &SR[0][0];
  float* redI = &SI[0][0];
  #pragma unroll
  for (int e = 0; e < 16; ++e){
    redR[t*16 + e] = gr[e>>2][e&3];
    redI[t*16 + e] = gi[e>>2][e&3];
  }
  __syncthreads();
  {
    const int tile2 = t >> 4, e2 = t & 15;
    float sr = 0.f, si = 0.f;
    for (int p = 0; p < 16; ++p){
      sr += redR[(p*16 + tile2)*16 + e2];
      si += redI[(p*16 + tile2)*16 + e2];
    }
    const int ii = (tile2 >> 2)*4 + (e2 >> 2);
    const int jj = (tile2 & 3)*4 + (e2 & 3);
    const float tm = prm[P_TEMP + h];
    const float sc = tm / (norms[b*128 + h*16 + ii] * norms[b*128 + h*16 + jj]);
    AR[ii][jj] = sr*sc;
    AI[ii][jj] = si*sc;
  }
  __syncthreads();
  if (t < 32){
    float* row = (t < 16) ? AR[t & 15] : AI[t & 15];
    float mx = row[0];
    for (int j2 = 1; j2 < 16; ++j2) mx = fmaxf(mx, row[j2]);
    float s = 0.f, e[16];
    for (int j2 = 0; j2 < 16; ++j2){ e[j2] = expf(row[j2] - mx); s += e[j2]; }
    float inv = 1.f/s;
    for (int j2 = 0; j2 < 16; ++j2) row[j2] = e[j2]*inv;
  }
  __syncthreads();
  {
    const int mi = t >> 4, mj = t & 15;
    float mr = 0.f, mim = 0.f;
    #pragma unroll
    for (int p = 0; p < 16; ++p){
      float sv, cv;
      sincospif((float)((mi*p) & 15)/8.0f, &sv, &cv);
      const float arv = AR[p][mj], aiv = AI[p][mj];
      mr  += cv*arv - sv*aiv;
      mim += cv*aiv + sv*arv;
    }
    wsM[bh*512 + t*2]     = mr*(1.f/16.f);
    wsM[bh*512 + t*2 + 1] = mim*(1.f/16.f);
  }
}

// ===================== gating MLP -> g plane (bf16) =====================
__global__ __launch_bounds__(256) void k_gate(const u16* __restrict__ Frb,
                                              const float* __restrict__ prm,
                                              u16* __restrict__ g){
  __shared__ float W1T[128][8];
  __shared__ float W2[128][8];
  __shared__ float B1v[8], S1v[8], BB1v[8];
  __shared__ float B2v[128];
  const int t = threadIdx.x;
  for (int i = t; i < 1024; i += 256){
    W1T[i & 127][i >> 7] = prm[P_W1 + i];
    W2[i >> 3][i & 7]    = prm[P_W2 + i];
  }
  if (t < 8){ B1v[t] = prm[P_B1+t]; S1v[t] = prm[P_S1+t]; BB1v[t] = prm[P_BB1+t]; }
  if (t < 128) B2v[t] = prm[P_B2+t];
  __syncthreads();
  const int pix = blockIdx.x*256 + t;
  const int b = pix >> 12, n = pix & 4095;
  const u16* fr = Frb + b*128*4096 + n;
  float q[8] = {};
  for (int c = 0; c < 128; ++c){
    const float v = bu2f(fr[c*4096]);
    float wa[4], wb[4];
    ld4a(wa, &W1T[c][0]); ld4a(wb, &W1T[c][4]);
    #pragma unroll
    for (int k = 0; k < 4; ++k){ q[k] = fmaf(wa[k], v, q[k]); q[4+k] = fmaf(wb[k], v, q[4+k]); }
  }
  float qa[8];
  #pragma unroll
  for (int k = 0; k < 8; ++k)
    qa[k] = fmaxf(fmaf(q[k] + B1v[k], S1v[k], BB1v[k]), 0.f);
  u16* grow = g + b*128*4096 + n;
  for (int c = 0; c < 128; ++c){
    float wa[4], wb[4];
    ld4a(wa, &W2[c][0]); ld4a(wb, &W2[c][4]);
    float acc = B2v[c];
    #pragma unroll
    for (int k = 0; k < 4; ++k) acc += wa[k]*qa[k] + wb[k]*qa[4+k];
    grow[c*4096] = f2bu(1.f/(1.f + expf(-acc)));
  }
}

// ===================== out_l = |ifft2(g*F)| + x via MFMA (channels 128..255) =====================
__global__ __launch_bounds__(256) void k_outl_m(const u16* __restrict__ Frb, const u16* __restrict__ Fib,
                                                const u16* __restrict__ g, const void* __restrict__ x,
                                                float* __restrict__ out, const u16* __restrict__ dft,
                                                const int* __restrict__ flg){
  __shared__ __align__(16) u16 TTr[64*72], TTi[64*72];
  const int bc = blockIdx.x, t = threadIdx.x;
  const int b = bc >> 7, c = bc & 127;
  const int lane = t & 63, wave = t >> 6;
  const int quad = lane >> 4, lr = lane & 15;
  const int f32m = __builtin_amdgcn_readfirstlane(*flg);
  const u16* EIr = dft + 8192;
  const u16* EIi = dft + 12288;
  const u16* pg = g   + bc*4096;
  const u16* pr = Frb + bc*4096;
  const u16* pi = Fib + bc*4096;
  // pass1: T[h][k2] = sum_w P[h][w] IF[k2][w], P = g*F; store T^T (k2-tile = wave)
  #pragma unroll
  for (int mi = 0; mi < 4; ++mi){
    f32x4 a1={0.f,0.f,0.f,0.f}, a2={0.f,0.f,0.f,0.f}, a3={0.f,0.f,0.f,0.f}, a4={0.f,0.f,0.f,0.f};
    #pragma unroll
    for (int ks = 0; ks < 2; ++ks){
      const int ao = (mi*16+lr)*64 + ks*32 + quad*8;
      short8 gv = *(const short8*)(pg + ao);
      short8 apr = mulpk(gv, *(const short8*)(pr + ao));
      short8 api = mulpk(gv, *(const short8*)(pi + ao));
      const int bo = (wave*16+lr)*64 + ks*32 + quad*8;
      short8 br = *(const short8*)(EIr + bo);
      short8 bi = *(const short8*)(EIi + bo);
      a1 = MF(apr, br, a1); a2 = MF(api, bi, a2);
      a3 = MF(apr, bi, a3); a4 = MF(api, br, a4);
    }
    f32x4 tr, ti;
    #pragma unroll
    for (int r = 0; r < 4; ++r){ tr[r] = a1[r]-a2[r]; ti[r] = a3[r]+a4[r]; }
    *(ushort4*)(TTr + (wave*16+lr)*72 + mi*16 + quad*4) = pk4(tr);
    *(ushort4*)(TTi + (wave*16+lr)*72 + mi*16 + quad*4) = pk4(ti);
  }
  __syncthreads();
  // pass2: Y^T[k2][k1] = sum_h T^T[k2][h] IF[k1][h]; out = |Y| + x
  #pragma unroll
  for (int nt = 0; nt < 4; ++nt){
    f32x4 a1={0.f,0.f,0.f,0.f}, a2={0.f,0.f,0.f,0.f}, a3={0.f,0.f,0.f,0.f}, a4={0.f,0.f,0.f,0.f};
    #pragma unroll
    for (int ks = 0; ks < 2; ++ks){
      short8 tr = *(const short8*)(TTr + (wave*16+lr)*72 + ks*32 + quad*8);
      short8 ti = *(const short8*)(TTi + (wave*16+lr)*72 + ks*32 + quad*8);
      const int bo = (nt*16+lr)*64 + ks*32 + quad*8;
      short8 br = *(const short8*)(EIr + bo);
      short8 bi = *(const short8*)(EIi + bo);
      a1 = MF(tr, br, a1); a2 = MF(ti, bi, a2);
      a3 = MF(tr, bi, a3); a4 = MF(ti, br, a4);
    }
    // D[m=k2=wave*16+quad*4+r][n=k1=nt*16+lr]
    const int o = (b*256 + 128 + c)*4096 + (nt*16+lr)*64 + wave*16 + quad*4;
    float xr[4];
    if (f32m) ld4a(xr, (const float*)x + o); else ld4b(xr, (const u16*)x + o);
    float ov[4];
    #pragma unroll
    for (int r = 0; r < 4; ++r){
      float yr = a1[r]-a2[r], yi = a3[r]+a4[r];
      ov[r] = sqrtf(yr*yr + yi*yi) + xr[r];
    }
    st4(out + o, ov);
  }
}

// ===================== 4096-pt IFFT via MFMA, four-step, in place =====================
__global__ __launch_bounds__(256) void k_ifft4096_m(u16* __restrict__ Frb, u16* __restrict__ Fib,
                                                    const float* __restrict__ ws,
                                                    const u16* __restrict__ dft){
  __shared__ __align__(16) u16 A2Tr[64*72], A2Ti[64*72], Cr[64*72], Ci[64*72];
  const int bc = blockIdx.x, t = threadIdx.x;
  const int lane = t & 63, wave = t >> 6;
  const int quad = lane >> 4, lr = lane & 15;
  const u16* EIr = dft + 8192;
  const u16* EIi = dft + 12288;
  const float* twr = ws + TABTW_RE;
  const float* twi = ws + TABTW_IM;
  u16* fr = Frb + bc*4096;
  u16* fi = Fib + bc*4096;
  // stage transpose: A2T[n2][n1] = F[n1][n2]
  for (int i = t; i < 4096; i += 256){
    int n1 = i >> 6, n2 = i & 63;
    A2Tr[n2*72 + n1] = fr[i];
    A2Ti[n2*72 + n1] = fi[i];
  }
  __syncthreads();
  // pass1: T[k1][n2] = sum_n1 IF[k1][n1] A2T[n2][n1]; twiddle -> C[k1][n2]  (k1-tile = wave)
  #pragma unroll
  for (int nt = 0; nt < 4; ++nt){
    f32x4 a1={0.f,0.f,0.f,0.f}, a2={0.f,0.f,0.f,0.f}, a3={0.f,0.f,0.f,0.f}, a4={0.f,0.f,0.f,0.f};
    #pragma unroll
    for (int ks = 0; ks < 2; ++ks){
      const int ao = (wave*16+lr)*64 + ks*32 + quad*8;
      short8 Ar = *(const short8*)(EIr + ao);
      short8 Ai = *(const short8*)(EIi + ao);
      short8 br = *(const short8*)(A2Tr + (nt*16+lr)*72 + ks*32 + quad*8);
      short8 bi = *(const short8*)(A2Ti + (nt*16+lr)*72 + ks*32 + quad*8);
      a1 = MF(Ar, br, a1); a2 = MF(Ai, bi, a2);
      a3 = MF(Ar, bi, a3); a4 = MF(Ai, br, a4);
    }
    // D[m=k1=wave*16+quad*4+r][n=n2=nt*16+lr]
    #pragma unroll
    for (int r = 0; r < 4; ++r){
      const int k1 = wave*16 + quad*4 + r;
      const int n2 = nt*16 + lr;
      const float trv = a1[r]-a2[r], tiv = a3[r]+a4[r];
      const float wr = twr[k1*64 + n2], wi = twi[k1*64 + n2];
      Cr[k1*72 + n2] = f2bu(trv*wr - tiv*wi);
      Ci[k1*72 + n2] = f2bu(trv*wi + tiv*wr);
    }
  }
  __syncthreads();
  // pass2: Z[k1][k2] = sum_n2 C[k1][n2] IF[k2][n2]; store flat = k2*64 + k1  (k1-tile = wave)
  #pragma unroll
  for (int nt = 0; nt < 4; ++nt){
    f32x4 a1={0.f,0.f,0.f,0.f}, a2={0.f,0.f,0.f,0.f}, a3={0.f,0.f,0.f,0.f}, a4={0.f,0.f,0.f,0.f};
    #pragma unroll
    for (int ks = 0; ks < 2; ++ks){
      short8 Ar = *(const short8*)(Cr + (wave*16+lr)*72 + ks*32 + quad*8);
      short8 Ai = *(const short8*)(Ci + (wave*16+lr)*72 + ks*32 + quad*8);
      const int bo = (nt*16+lr)*64 + ks*32 + quad*8;
      short8 br = *(const short8*)(EIr + bo);
      short8 bi = *(const short8*)(EIi + bo);
      a1 = MF(Ar, br, a1); a2 = MF(Ai, bi, a2);
      a3 = MF(Ar, bi, a3); a4 = MF(Ai, br, a4);
    }
    f32x4 zr, zi;
    #pragma unroll
    for (int r = 0; r < 4; ++r){ zr[r] = a1[r]-a2[r]; zi[r] = a3[r]+a4[r]; }
    // D[m=k1=wave*16+quad*4+r][n=k2=nt*16+lr]; flat = k2*64 + k1 -> 4 consecutive k1
    const int flat = (nt*16+lr)*64 + wave*16 + quad*4;
    *(ushort4*)(fr + flat) = pk4(zr);
    *(ushort4*)(fi + flat) = pk4(zi);
  }
}

// ===================== out_f = |M @ Z| + x  (channels 0..127), f32 out =====================
__global__ __launch_bounds__(256) void k_outf(const u16* __restrict__ Zr, const u16* __restrict__ Zi,
                                              const float* __restrict__ wsM, const void* __restrict__ x,
                                              float* __restrict__ out, const int* __restrict__ flg){
  __shared__ float MreT[16][20], MimT[16][20];
  const int gb = blockIdx.x;
  const int bh = gb & 127, nch = gb >> 7;
  const int b = bh >> 3, h = bh & 7;
  const int t = threadIdx.x;
  const int f32m = __builtin_amdgcn_readfirstlane(*flg);
  {
    const int i = t >> 4, j = t & 15;
    MreT[j][i] = wsM[bh*512 + t*2];
    MimT[j][i] = wsM[bh*512 + t*2 + 1];
  }
  __syncthreads();
  const int i0 = (t & 3)*4;
  const int nn = nch*256 + (t >> 2)*4;
  const u16* zr = Zr + (b*128 + h*16)*4096 + nn;
  const u16* zi = Zi + (b*128 + h*16)*4096 + nn;
  float accr[4][4] = {}, acci[4][4] = {};
  #pragma unroll
  for (int j = 0; j < 16; ++j){
    float mr[4], mi[4], vr[4], vi[4];
    ld4a(mr, &MreT[j][i0]);
    ld4a(mi, &MimT[j][i0]);
    ld4b(vr, zr + j*4096);
    ld4b(vi, zi + j*4096);
    #pragma unroll
    for (int i = 0; i < 4; ++i)
      #pragma unroll
      for (int n = 0; n < 4; ++n){
        accr[i][n] += mr[i]*vr[n] - mi[i]*vi[n];
        acci[i][n] += mr[i]*vi[n] + mi[i]*vr[n];
      }
  }
  #pragma unroll
  for (int i = 0; i < 4; ++i){
    const int o = (b*256 + h*16 + i0 + i)*4096 + nn;
    float xr[4];
    if (f32m) ld4a(xr, (const float*)x + o); else ld4b(xr, (const u16*)x + o);
    float ov[4];
    #pragma unroll
    for (int n = 0; n < 4; ++n)
      ov[n] = sqrtf(accr[i][n]*accr[i][n] + acci[i][n]*acci[i][n]) + xr[n];
    st4(out + o, ov);
  }
}

// ===================== launch =====================
extern "C" void kernel_launch(void* const* d_in, const int* in_sizes, int n_in,
                              void* d_out, int out_size, void* d_ws, size_t ws_size,
                              hipStream_t stream) {
  const void* x        = d_in[0];
  const void* conv2_w  = d_in[1];
  const void* conv2_b  = d_in[2];
  const void* bn2_s    = d_in[3];
  const void* bn2_b    = d_in[4];
  const void* temp     = d_in[5];
  const void* w1_w     = d_in[6];
  const void* w1_b     = d_in[7];
  const void* bnw_s    = d_in[8];
  const void* bnw_b    = d_in[9];
  const void* w2_w     = d_in[10];
  const void* w2_b     = d_in[11];
  float* out = (float*)d_out;
  float* wsf = (float*)d_ws;

  if (ws_size < (size_t)(F32_END*4) + 3u*(size_t)BPLANE*2u) return;

  int* flag = (int*)(wsf + FLAG_OFF);
  float* prm = wsf + PRM_OFF;
  u16* wT2 = (u16*)(wsf + WT_OFF);
  u16* dft = (u16*)(wsf + DFT16_OFF);
  u16* wsb = (u16*)(wsf + F32_END);
  u16* Frb = wsb;
  u16* Fib = wsb + BPLANE;
  u16* xt  = wsb;              // aliases Frb+Fib (dead before k_fft2_m writes them)
  u16* Ab  = wsb + 2*BPLANE;   // conv output; later aliased by g
  u16* g   = Ab;

  k_detect<<<1, 64, 0, stream>>>((const u16*)x, flag);
  k_tables<<<16, 256, 0, stream>>>(wsf);
  k_dftprep<<<16, 256, 0, stream>>>(dft);
  k_pack<<<1, 256, 0, stream>>>(conv2_b, bn2_s, bn2_b, temp, w1_w, w1_b, bnw_s, bnw_b,
                                w2_w, w2_b, flag, prm);
  k_wprep2<<<1152, 256, 0, stream>>>(conv2_w, wT2, prm, flag);
  k_trans<<<1024, 256, 0, stream>>>(x, xt, flag);
  k_cmm<<<256, 256, 0, stream>>>(xt, wT2, prm, Ab);
  k_fft2_m<<<2048, 256, 0, stream>>>(Ab, Frb, Fib, dft);
  k_norms<<<2048, 256, 0, stream>>>(Frb, Fib, wsf + NORMS_OFF);
  k_attn<<<128, 256, 0, stream>>>(Frb, Fib, wsf + NORMS_OFF, prm, wsf + MMAT_OFF);
  k_gate<<<256, 256, 0, stream>>>(Frb, prm, g);
  k_outl_m<<<2048, 256, 0, stream>>>(Frb, Fib, g, x, out, dft, flag);
  k_ifft4096_m<<<2048, 256, 0, stream>>>(Frb, Fib, wsf, dft);
  k_outf<<<2048, 256, 0, stream>>>(Frb, Fib, wsf + MMAT_OFF, x, out, flag);
}